// Round 3
// baseline (466.010 us; speedup 1.0000x reference)
//
#include <hip/hip_runtime.h>
#include <math.h>

#define KK 8
#define H 250          // SIZE == h1
#define MDIM 576
#define NB 2048
#define HA 100
#define ROWS (NB*KK)   // 16384
#define PQS 512        // PQb row stride (ushort): P at 0..249, Q at 256..505
#define KP 1088        // padded K for out GEMM (1076 -> 34*32)
#define EPS 1e-5f

typedef unsigned short ushort_t;
typedef short short8 __attribute__((ext_vector_type(8)));
typedef unsigned short us8 __attribute__((ext_vector_type(8)));
typedef unsigned short us4 __attribute__((ext_vector_type(4)));
typedef unsigned short us2 __attribute__((ext_vector_type(2)));
typedef float f32x4 __attribute__((ext_vector_type(4)));

// ---- DPP helpers (old=0 + bound_ctrl=1 so GCNDPPCombine folds to v_add_f32_dpp) ----
template<int CTRL>
__device__ __forceinline__ float dpp_add_f32(float x) {
    const int s = __builtin_amdgcn_update_dpp(
        0, __builtin_bit_cast(int, x), CTRL, 0xF, 0xF, true);
    return x + __builtin_bit_cast(float, s);
}
// full-wave (64-lane) sum; result broadcast wave-uniform via readlane(63)
__device__ __forceinline__ float wave_sum_dpp(float x) {
    x = dpp_add_f32<0x111>(x);  // row_shr:1
    x = dpp_add_f32<0x112>(x);  // row_shr:2
    x = dpp_add_f32<0x114>(x);  // row_shr:4
    x = dpp_add_f32<0x118>(x);  // row_shr:8
    x = dpp_add_f32<0x142>(x);  // row_bcast:15
    x = dpp_add_f32<0x143>(x);  // row_bcast:31 -> lane 63 holds total
    return __builtin_bit_cast(float, __builtin_amdgcn_readlane(
        __builtin_bit_cast(int, x), 63));
}
// 16-lane butterfly sum: result present in ALL 16 lanes of each 16-lane row
__device__ __forceinline__ float bfly16_sum(float x) {
    x = dpp_add_f32<0xB1>(x);   // quad_perm [1,0,3,2]  (xor 1)
    x = dpp_add_f32<0x4E>(x);   // quad_perm [2,3,0,1]  (xor 2)
    x = dpp_add_f32<0x141>(x);  // row_half_mirror      (pairs across quads)
    x = dpp_add_f32<0x140>(x);  // row_mirror           (pairs across halves)
    return x;
}

__device__ __forceinline__ void async_copy16(const void* g, void* l) {
    __builtin_amdgcn_global_load_lds(
        (const __attribute__((address_space(1))) void*)g,
        (__attribute__((address_space(3))) void*)l, 16, 0, 0);
}

__device__ __forceinline__ ushort_t f2bf(float v) {
    union { float f; unsigned int u; } c; c.f = v;
    unsigned int x = c.u;
    x += 0x7fff + ((x >> 16) & 1);   // RNE
    return (ushort_t)(x >> 16);
}
__device__ __forceinline__ float bf2f(ushort_t v) {
    union { unsigned int u; float f; } c; c.u = ((unsigned int)v) << 16;
    return c.f;
}
// fast tanh: 1 - 2/(exp(2x)+1)  (v_exp + v_rcp; ~1e-6 rel err, << bf16 ulp)
__device__ __forceinline__ float ftanh(float x) {
    const float e = __expf(2.f * x);
    return 1.f - 2.f * __builtin_amdgcn_rcpf(e + 1.f);
}
__device__ __forceinline__ float fsigmoid(float x) {
    return __builtin_amdgcn_rcpf(1.f + __expf(-x));
}

// ---- fused prep: Wt | Wpq | Wca | Wenc | Sb | x->Abuf ----
__global__ __launch_bounds__(256) void k_prep(
    const float* __restrict__ out_W, const float* __restrict__ core_W,
    const float* __restrict__ ctx_W, const float* __restrict__ att_W1,
    const float* __restrict__ enc_W, const float* __restrict__ state,
    const float* __restrict__ x,
    ushort_t* __restrict__ Wt, ushort_t* __restrict__ Wpq,
    ushort_t* __restrict__ Wca, ushort_t* __restrict__ Wenc,
    ushort_t* __restrict__ Sb, ushort_t* __restrict__ Abuf)
{
    const int b = blockIdx.x, t = threadIdx.x;
    if (b < 256) {                      // Wt[n][k] = out_W[k][n]
        const int n = b;
        for (int k = t; k < KP; k += 256) {
            const float v = (n < H && k < 1076) ? out_W[(size_t)k * H + n] : 0.f;
            Wt[(size_t)n * KP + k] = f2bf(v);
        }
    } else if (b < 768) {               // Wpq
        const int n = b - 256, k = t;
        float v = 0.f;
        if (k < H) {
            if (n < H)                    v = core_W[(size_t)k * H + n];
            else if (n >= 256 && n < 506) v = core_W[(size_t)(H + k) * H + (n - 256)];
        }
        Wpq[(size_t)n * 256 + k] = f2bf(v);
    } else if (b < 1152) {              // Wca
        const int n = b - 768, k = t;
        float v = 0.f;
        if (k < H) {
            if (n < H)           v = ctx_W[(size_t)k * H + n];
            else if (n < H + HA) v = att_W1[(size_t)k * HA + (n - H)];
        }
        Wca[(size_t)n * 256 + k] = f2bf(v);
    } else if (b < 1408) {              // Wenc[n][k] = enc_W[k][n]
        const int n = b - 1152, k = t;
        const float v = (n < H && k < H) ? enc_W[(size_t)k * H + n] : 0.f;
        Wenc[(size_t)n * 256 + k] = f2bf(v);
    } else if (b < 2432) {              // Sb: state padded to 256, bf16
        const int r0 = (b - 1408) * 16;
        for (int idx = t; idx < 16 * 256; idx += 256) {
            const int r = r0 + (idx >> 8), k = idx & 255;
            const float v = (k < H) ? state[(size_t)r * H + k] : 0.f;
            Sb[(size_t)r * 256 + k] = f2bf(v);
        }
    } else {                            // Abuf cols [500,1088): x + pad
        const int row = b - 2432;
        for (int c = 500 + t; c < KP; c += 256) {
            const float v = (c < 500 + MDIM) ? x[(size_t)row * MDIM + (c - 500)] : 0.f;
            Abuf[(size_t)row * KP + c] = f2bf(v);
        }
    }
}

// N-resident bf16 MFMA GEMM (k_cs-style): C[m][n] = sum_k A[m][k]*B[n][k] (+bias)
// Whole N = NT*64 resident in LDS per block -> A fetched exactly once.
// 512 thr = 8 waves (2m x 4n); per wave 32 rows x NT*16 cols; acc[2][NT].
template<int NT>
__global__ __launch_bounds__(512, NT == 8 ? 2 : 4) void k_gemm_nres(
    const ushort_t* __restrict__ A, int lda,
    const ushort_t* __restrict__ B, int ldb,
    void* __restrict__ Cp, int ldc,
    const float* __restrict__ bias,
    int ksteps, int nlim, int bf16out)
{
    constexpr int NROWS = NT * 64;                    // B rows resident
    __shared__ __align__(16) ushort_t As[64 * 32];    // 4 KB
    __shared__ __align__(16) ushort_t Bs[NROWS * 32]; // NT*4 KB
    const int tid = threadIdx.x, lane = tid & 63, wave = tid >> 6;
    const int wm = wave >> 2, wn = wave & 3;
    const int R0 = (int)blockIdx.x * 64;

    const int ar = tid >> 2, acb = tid & 3;
    const bool aon = tid < 256;
    const int acl = acb ^ ((ar >> 1) & 3);
    const ushort_t* gA = A + (size_t)(R0 + ar) * lda + acl * 8;

    const int q = lane >> 4, fr = lane & 15;

    f32x4 acc[2][NT] = {};
    for (int ks = 0; ks < ksteps; ++ks) {
        const int k0 = ks * 32;
        if (aon) async_copy16(gA + k0, &As[tid * 8]);
#pragma unroll
        for (int it = 0; it < NT / 2; ++it) {
            const int ci  = it * 512 + tid;
            const int rb  = ci >> 2, cb2 = ci & 3;
            const int clb = cb2 ^ ((rb >> 1) & 3);
            async_copy16(B + (size_t)rb * ldb + k0 + clb * 8, &Bs[ci * 8]);
        }
        __syncthreads();
        short8 a[2];
#pragma unroll
        for (int ms = 0; ms < 2; ++ms) {
            const int row = wm * 32 + ms * 16 + fr;
            a[ms] = *(const short8*)&As[(row * 4 + (q ^ ((row >> 1) & 3))) * 8];
        }
#pragma unroll
        for (int nt = 0; nt < NT; ++nt) {
            const int n = wn * (NT * 16) + nt * 16 + fr;
            const short8 b = *(const short8*)&Bs[(n * 4 + (q ^ ((n >> 1) & 3))) * 8];
#pragma unroll
            for (int ms = 0; ms < 2; ++ms)
                acc[ms][nt] = __builtin_amdgcn_mfma_f32_16x16x32_bf16(
                    a[ms], b, acc[ms][nt], 0, 0, 0);
        }
        __syncthreads();
    }

#pragma unroll
    for (int ms = 0; ms < 2; ++ms)
#pragma unroll
        for (int nt = 0; nt < NT; ++nt) {
            const int col = wn * (NT * 16) + nt * 16 + fr;
            if (col >= nlim) continue;
            const float bv = bias ? bias[col] : 0.f;
#pragma unroll
            for (int reg = 0; reg < 4; ++reg) {
                const int row = R0 + wm * 32 + ms * 16 + q * 4 + reg;
                const float v = acc[ms][nt][reg] + bv;
                if (bf16out) ((ushort_t*)Cp)[(size_t)row * ldc + col] = f2bf(v);
                else         ((float*)Cp)[(size_t)row * ldc + col] = v;
            }
        }
}

// LN(relu(Epre + enc_b)) -> Abuf cols [0,250). One wave per row, us4 loads.
__global__ __launch_bounds__(256) void k_lnenc(const ushort_t* __restrict__ Epre,
    const float* __restrict__ eb, const float* __restrict__ eg,
    const float* __restrict__ ebt, ushort_t* __restrict__ Abuf)
{
    const int wave = threadIdx.x >> 6, lane = threadIdx.x & 63;
    const int row = blockIdx.x * 4 + wave;
    const int c0 = 4 * lane;

    const us4 v = *(const us4*)&Epre[(size_t)row * 256 + c0];
    float y[4]; float sm = 0.f, sq = 0.f;
#pragma unroll
    for (int t = 0; t < 4; ++t) {
        const int cc = c0 + t;
        float z = 0.f;
        if (cc < H) z = fmaxf(bf2f(v[t]) + eb[cc], 0.f);
        y[t] = z; sm += z; sq += z * z;
    }
    sm = wave_sum_dpp(sm);
    sq = wave_sum_dpp(sq);
    const float mu = sm * (1.f / H);
    const float rs = __builtin_amdgcn_rsqf(sq * (1.f / H) - mu * mu + EPS);
    ushort_t o[4];
#pragma unroll
    for (int t = 0; t < 4; ++t) {
        const int cc = c0 + t;
        o[t] = (cc < H) ? f2bf((y[t] - mu) * rs * eg[cc] + ebt[cc]) : (ushort_t)0;
    }
    ushort_t* dst = Abuf + (size_t)row * KP + c0;
    if (c0 + 3 < H) { *(us4*)dst = (us4){o[0], o[1], o[2], o[3]}; }
    else {
        if (c0 + 1 < H) *(us2*)dst = (us2){o[0], o[1]};
    }
}

// ================= mega-fused core+cs+eff =================
// Block = 32 groups (4 octets). Loop jj=0..6:
//   1) A rows (32x256) = LN(relu(P[g] + Q[partner] + core_b)) in LDS —
//      wave-per-row (4 passes x 8 waves), k_core's exact per-row math,
//      wave_sum_dpp; us4 store with pair-preserving 8B-slot swizzle
//      p = ((s>>1) ^ (r&7))*2 + (s&1)  [16B-chunk read swizzle: c ^ (r&7)].
//   2) GEMM A @ Wca^T, M=32 N=384 K=256 (k_cs staging, uniform per-ks).
//   3) fragment-level relu/tanh + bfly16 over fr + cross-wave LDS reduce ->
//      per-row sigmoid gate; accumulate A4/S0/S1 in registers across jj.
// Final: eff rows -> Abuf cols [250,500).
__global__ __launch_bounds__(512, 4) void k_fuse(
    const ushort_t* __restrict__ PQb,
    const ushort_t* __restrict__ Wca,   // [384][256] bf16
    const float* __restrict__ core_b, const float* __restrict__ core_g,
    const float* __restrict__ core_bt,
    const float* __restrict__ ctx_b, const float* __restrict__ ctx_g,
    const float* __restrict__ ctx_bt,
    const float* __restrict__ att_b1, const float* __restrict__ att_g,
    const float* __restrict__ att_bt,
    const float* __restrict__ attW2, const float* __restrict__ att_b2,
    ushort_t* __restrict__ Abuf)
{
    __shared__ __align__(16) ushort_t As[32 * 256];  // 16 KB, slot-swizzled
    __shared__ __align__(16) ushort_t Bs[384 * 32];  // 24 KB per k-step
    __shared__ __align__(16) float red[32][36];      // [row][wn*8 + v]
    __shared__ __align__(16) float scal[32][4];      // cj, ag, cj*muC
    __shared__ float swred[4][2];

    const int tid = threadIdx.x, lane = tid & 63, wave = tid >> 6;
    const int wm = wave >> 2, wn = wave & 3;
    const int q = lane >> 4, fr = lane & 15;
    const int g0 = (int)blockIdx.x * 32;

    // ---- per-lane per-col constants for the 6 nt tiles (epilogue) ----
    bool eC[6], eA[6];
    float b_[6], g_[6], bt_[6], gw[6];
    float psgw = 0.f, psbw = 0.f;
#pragma unroll
    for (int nt = 0; nt < 6; ++nt) {
        const int col = wn * 96 + nt * 16 + fr;
        eC[nt] = col < H;
        eA[nt] = (col >= H) && (col < H + HA);
        if (eC[nt]) {
            b_[nt] = ctx_b[col]; g_[nt] = ctx_g[col]; bt_[nt] = ctx_bt[col]; gw[nt] = 0.f;
        } else if (eA[nt]) {
            const int ca = col - H;
            b_[nt] = att_b1[ca]; g_[nt] = att_g[ca]; bt_[nt] = att_bt[ca];
            const float w2 = attW2[ca];
            gw[nt] = g_[nt] * w2;
            psgw += gw[nt]; psbw += bt_[nt] * w2;
        } else {
            b_[nt] = g_[nt] = bt_[nt] = gw[nt] = 0.f;
        }
    }
    // row-invariant attention sums (fr-butterfly + cross-wave via LDS)
    psgw = bfly16_sum(psgw); psbw = bfly16_sum(psbw);
    if (lane == 0) { swred[wn][0] = psgw; swred[wn][1] = psbw; }  // wm dup: benign
    __syncthreads();
    const float sgw = swred[0][0] + swred[1][0] + swred[2][0] + swred[3][0];
    const float ab2 = att_b2[0] +
        (swred[0][1] + swred[1][1] + swred[2][1] + swred[3][1]);

    // ---- phase-1 jj-invariant state: lane's 4 cols, P fragments ----
    const int cL = lane * 4;
    float cb4[4], cg4[4], cbt4[4]; bool vl4[4];
#pragma unroll
    for (int t = 0; t < 4; ++t) {
        vl4[t] = (cL + t) < H;
        cb4[t] = cg4[t] = cbt4[t] = 0.f;
        if (vl4[t]) { cb4[t] = core_b[cL + t]; cg4[t] = core_g[cL + t];
                      cbt4[t] = core_bt[cL + t]; }
    }
    us4 puR[4];
#pragma unroll
    for (int pass = 0; pass < 4; ++pass) {
        const int r = pass * 8 + wave;
        puR[pass] = *(const us4*)&PQb[(size_t)(g0 + r) * PQS + cL];
    }
    // swizzled LDS slot for this lane (slot s = lane): position within row
    const int pSlot = (((lane >> 1) ^ 0) << 1) | (lane & 1);  // row-XOR applied per pass
    (void)pSlot;

    // GEMM A-read addressing
    const int arow = wm * 16 + fr;
    const int abase = arow * 256;
    const int arsw = arow & 7;

    f32x4 A4[6] = {};
    float S0[4] = {0.f, 0.f, 0.f, 0.f}, S1[4] = {0.f, 0.f, 0.f, 0.f};

    for (int jj = 0; jj < 7; ++jj) {
        // ---- phase 1: build A rows = LN(relu(P+Q+core_b)), wave-per-row ----
#pragma unroll
        for (int pass = 0; pass < 4; ++pass) {
            const int r = pass * 8 + wave;
            const int ir = r & 7;
            const int j = jj + (jj >= ir ? 1 : 0);
            const us4 qu = *(const us4*)&PQb[
                (size_t)(g0 + (r & ~7) + j) * PQS + 256 + cL];
            const us4 pu = puR[pass];
            float z[4]; float sm = 0.f, sq = 0.f;
#pragma unroll
            for (int t = 0; t < 4; ++t) {
                float zz = 0.f;
                if (vl4[t]) zz = fmaxf(bf2f(pu[t]) + bf2f(qu[t]) + cb4[t], 0.f);
                z[t] = zz; sm += zz; sq = fmaf(zz, zz, sq);
            }
            sm = wave_sum_dpp(sm);
            sq = wave_sum_dpp(sq);
            const float mu = sm * (1.f / H);
            const float rs = __builtin_amdgcn_rsqf(sq * (1.f / H) - mu * mu + EPS);
            us4 o;
#pragma unroll
            for (int t = 0; t < 4; ++t)
                o[t] = vl4[t] ? f2bf((z[t] - mu) * rs * cg4[t] + cbt4[t])
                              : (ushort_t)0;
            const int p = (((lane >> 1) ^ (r & 7)) << 1) | (lane & 1);
            *(us4*)&As[r * 256 + p * 4] = o;
        }

        // ---- phase 2: GEMM M=32 N=384 K=256 (uniform per-ks staging) ----
        f32x4 acc[6] = {};
        for (int ks = 0; ks < 8; ++ks) {
#pragma unroll
            for (int it = 0; it < 3; ++it) {
                const int ci  = it * 512 + tid;
                const int rb  = ci >> 2, cb2 = ci & 3;
                const int clb = cb2 ^ ((rb >> 1) & 3);
                async_copy16(Wca + (size_t)rb * 256 + ks * 32 + clb * 8, &Bs[ci * 8]);
            }
            __syncthreads();   // Bs(ks) staged; As ready (jj's ds_writes drained)
            const short8 a = *(const short8*)&As[abase + ((ks * 4 + q) ^ arsw) * 8];
#pragma unroll
            for (int nt = 0; nt < 6; ++nt) {
                const int n = wn * 96 + nt * 16 + fr;
                const short8 b = *(const short8*)&Bs[(n * 4 + (q ^ ((n >> 1) & 3))) * 8];
                acc[nt] = __builtin_amdgcn_mfma_f32_16x16x32_bf16(a, b, acc[nt], 0, 0, 0);
            }
            __syncthreads();   // Bs reads done
        }

        // ---- phase 3: transform + per-row reductions + gate ----
        float smc[4] = {}, sqc[4] = {}, sma[4] = {}, sqa[4] = {}, szgw[4] = {};
#pragma unroll
        for (int nt = 0; nt < 6; ++nt) {
#pragma unroll
            for (int reg = 0; reg < 4; ++reg) {
                const float val = acc[nt][reg] + b_[nt];
                if (eC[nt]) {
                    const float zz = fmaxf(val, 0.f);
                    acc[nt][reg] = zz;
                    smc[reg] += zz; sqc[reg] = fmaf(zz, zz, sqc[reg]);
                } else if (eA[nt]) {
                    const float za = ftanh(val);
                    sma[reg] += za; sqa[reg] = fmaf(za, za, sqa[reg]);
                    szgw[reg] = fmaf(za, gw[nt], szgw[reg]);
                }
            }
        }
#pragma unroll
        for (int reg = 0; reg < 4; ++reg) {
            smc[reg]  = bfly16_sum(smc[reg]);
            sqc[reg]  = bfly16_sum(sqc[reg]);
            sma[reg]  = bfly16_sum(sma[reg]);
            sqa[reg]  = bfly16_sum(sqa[reg]);
            szgw[reg] = bfly16_sum(szgw[reg]);
        }
        if (fr == 0) {
#pragma unroll
            for (int reg = 0; reg < 4; ++reg) {
                const int row = wm * 16 + q * 4 + reg;
                *(f32x4*)&red[row][wn * 8] =
                    (f32x4){smc[reg], sqc[reg], sma[reg], sqa[reg]};
                red[row][wn * 8 + 4] = szgw[reg];
            }
        }
        __syncthreads();
        if (wave == 0 && lane < 32) {
            const int rr = lane;
            float s0 = 0.f, s1 = 0.f, s2 = 0.f, s3 = 0.f, s4 = 0.f;
#pragma unroll
            for (int w2 = 0; w2 < 4; ++w2) {
                const f32x4 v = *(const f32x4*)&red[rr][w2 * 8];
                s0 += v[0]; s1 += v[1]; s2 += v[2]; s3 += v[3];
                s4 += red[rr][w2 * 8 + 4];
            }
            const float muC = s0 * (1.f / H);
            const float rsC = __builtin_amdgcn_rsqf(s1 * (1.f / H) - muC * muC + EPS);
            const float muA = s2 * (1.f / HA);
            const float rsA = __builtin_amdgcn_rsqf(s3 * (1.f / HA) - muA * muA + EPS);
            const float dot = rsA * (s4 - muA * sgw) + ab2;
            const float ag  = fsigmoid(dot);
            const float cj  = ag * rsC;
            *(f32x4*)&scal[rr][0] = (f32x4){cj, ag, cj * muC, 0.f};
        }
        __syncthreads();
#pragma unroll
        for (int reg = 0; reg < 4; ++reg) {
            const int row = wm * 16 + q * 4 + reg;
            const f32x4 sc = *(const f32x4*)&scal[row][0];
            S0[reg] += sc[1]; S1[reg] += sc[2];
#pragma unroll
            for (int nt = 0; nt < 6; ++nt)
                A4[nt][reg] = fmaf(sc[0], acc[nt][reg], A4[nt][reg]);
        }
    } // jj

    // ---- final write: eff -> Abuf cols [250, 500) ----
#pragma unroll
    for (int nt = 0; nt < 6; ++nt) {
        const int col = wn * 96 + nt * 16 + fr;
        if (col >= H) continue;
#pragma unroll
        for (int reg = 0; reg < 4; ++reg) {
            const int row = wm * 16 + q * 4 + reg;
            const float o = g_[nt] * (A4[nt][reg] - S1[reg]) + bt_[nt] * S0[reg];
            Abuf[(size_t)(g0 + row) * KP + H + col] = f2bf(o);
        }
    }
}

extern "C" void kernel_launch(void* const* d_in, const int* in_sizes, int n_in,
                              void* d_out, int out_size, void* d_ws, size_t ws_size,
                              hipStream_t stream)
{
    const float* x      = (const float*)d_in[0];
    const float* state  = (const float*)d_in[1];
    const float* enc_W  = (const float*)d_in[2];
    const float* enc_b  = (const float*)d_in[3];
    const float* enc_g  = (const float*)d_in[4];
    const float* enc_bt = (const float*)d_in[5];
    const float* core_W = (const float*)d_in[6];
    const float* core_b = (const float*)d_in[7];
    const float* core_g = (const float*)d_in[8];
    const float* core_bt= (const float*)d_in[9];
    const float* ctx_W  = (const float*)d_in[10];
    const float* ctx_b  = (const float*)d_in[11];
    const float* ctx_g  = (const float*)d_in[12];
    const float* ctx_bt = (const float*)d_in[13];
    const float* att_W1 = (const float*)d_in[14];
    const float* att_b1 = (const float*)d_in[15];
    const float* att_g  = (const float*)d_in[16];
    const float* att_bt = (const float*)d_in[17];
    const float* att_W2 = (const float*)d_in[18];
    const float* att_b2 = (const float*)d_in[19];
    const float* out_W  = (const float*)d_in[20];
    const float* out_b  = (const float*)d_in[21];
    float* out = (float*)d_out;

    // workspace layout (ushort units) — Co/Cs eliminated by k_fuse
    ushort_t* Abuf = (ushort_t*)d_ws;                   // 16384*1088  (35.7 MB)
    ushort_t* Wt   = Abuf + (size_t)ROWS * KP;          // 256*1088
    ushort_t* Wpq  = Wt + (size_t)256 * KP;             // 512*256
    ushort_t* Wca  = Wpq + (size_t)512 * 256;           // 384*256
    ushort_t* Wenc = Wca + (size_t)384 * 256;           // 256*256
    ushort_t* Sb   = Wenc + (size_t)256 * 256;          // 16384*256   (8 MB)
    ushort_t* Epre = Sb + (size_t)ROWS * 256;           // 16384*256   (8 MB)
    ushort_t* PQb  = Epre + (size_t)ROWS * 256;         // 16384*512   (16 MB)

    k_prep  <<<2432 + ROWS, 256, 0, stream>>>(out_W, core_W, ctx_W, att_W1, enc_W,
                                              state, x, Wt, Wpq, Wca, Wenc, Sb, Abuf);
    // Epre = state @ enc_W  (bf16 MFMA, N=256 resident)
    k_gemm_nres<4><<<ROWS / 64, 512, 0, stream>>>(Sb, 256, Wenc, 256, Epre, 256,
                                                  nullptr, 8, 256, 1);
    k_lnenc <<<ROWS / 4, 256, 0, stream>>>(Epre, enc_b, enc_g, enc_bt, Abuf);
    // PQb = s1 @ [W_top | W_bot]  (bf16 MFMA, N=512 resident, bf16 out)
    k_gemm_nres<8><<<ROWS / 64, 512, 0, stream>>>(Abuf, KP, Wpq, 256, PQb, PQS,
                                                  nullptr, 8, 512, 1);
    // fused core -> cs -> eff
    k_fuse  <<<ROWS / 32, 512, 0, stream>>>(PQb, Wca,
                                            core_b, core_g, core_bt,
                                            ctx_b, ctx_g, ctx_bt,
                                            att_b1, att_g, att_bt,
                                            att_W2, att_b2, Abuf);
    // out = [s1 | eff | x] @ out_W + b  (bf16 MFMA, N=256 resident, fp32 out)
    k_gemm_nres<4><<<ROWS / 64, 512, 0, stream>>>(Abuf, KP, Wt, KP, out, H,
                                                  out_b, KP / 32, 250, 0);
}

// Round 4
// 379.613 us; speedup vs baseline: 1.2276x; 1.2276x over previous
//
#include <hip/hip_runtime.h>
#include <math.h>

#define KK 8
#define H 250          // SIZE == h1
#define MDIM 576
#define NB 2048
#define HA 100
#define ROWS (NB*KK)   // 16384
#define PQS 512        // PQb row stride (ushort): P at 0..249, Q at 256..505
#define KP 1088        // padded K for out GEMM (1076 -> 34*32)
#define EFS 258        // effacc row stride (f32): 256+2 -> q-rows 8 banks apart
#define EPS 1e-5f

typedef unsigned short ushort_t;
typedef short short8 __attribute__((ext_vector_type(8)));
typedef unsigned short us8 __attribute__((ext_vector_type(8)));
typedef unsigned short us4 __attribute__((ext_vector_type(4)));
typedef unsigned short us2 __attribute__((ext_vector_type(2)));
typedef float f32x4 __attribute__((ext_vector_type(4)));

// ---- DPP helpers (old=0 + bound_ctrl=1 so GCNDPPCombine folds to v_add_f32_dpp) ----
template<int CTRL>
__device__ __forceinline__ float dpp_add_f32(float x) {
    const int s = __builtin_amdgcn_update_dpp(
        0, __builtin_bit_cast(int, x), CTRL, 0xF, 0xF, true);
    return x + __builtin_bit_cast(float, s);
}
// full-wave (64-lane) sum; result broadcast wave-uniform via readlane(63)
__device__ __forceinline__ float wave_sum_dpp(float x) {
    x = dpp_add_f32<0x111>(x);  // row_shr:1
    x = dpp_add_f32<0x112>(x);  // row_shr:2
    x = dpp_add_f32<0x114>(x);  // row_shr:4
    x = dpp_add_f32<0x118>(x);  // row_shr:8
    x = dpp_add_f32<0x142>(x);  // row_bcast:15
    x = dpp_add_f32<0x143>(x);  // row_bcast:31 -> lane 63 holds total
    return __builtin_bit_cast(float, __builtin_amdgcn_readlane(
        __builtin_bit_cast(int, x), 63));
}
// 16-lane butterfly sum: result present in ALL 16 lanes of each 16-lane row
__device__ __forceinline__ float bfly16_sum(float x) {
    x = dpp_add_f32<0xB1>(x);   // quad_perm [1,0,3,2]  (xor 1)
    x = dpp_add_f32<0x4E>(x);   // quad_perm [2,3,0,1]  (xor 2)
    x = dpp_add_f32<0x141>(x);  // row_half_mirror      (pairs across quads)
    x = dpp_add_f32<0x140>(x);  // row_mirror           (pairs across halves)
    return x;
}

__device__ __forceinline__ void async_copy16(const void* g, void* l) {
    __builtin_amdgcn_global_load_lds(
        (const __attribute__((address_space(1))) void*)g,
        (__attribute__((address_space(3))) void*)l, 16, 0, 0);
}

__device__ __forceinline__ ushort_t f2bf(float v) {
    union { float f; unsigned int u; } c; c.f = v;
    unsigned int x = c.u;
    x += 0x7fff + ((x >> 16) & 1);   // RNE
    return (ushort_t)(x >> 16);
}
__device__ __forceinline__ float bf2f(ushort_t v) {
    union { unsigned int u; float f; } c; c.u = ((unsigned int)v) << 16;
    return c.f;
}
// fast tanh: 1 - 2/(exp(2x)+1)  (v_exp + v_rcp; ~1e-6 rel err, << bf16 ulp)
__device__ __forceinline__ float ftanh(float x) {
    const float e = __expf(2.f * x);
    return 1.f - 2.f * __builtin_amdgcn_rcpf(e + 1.f);
}
__device__ __forceinline__ float fsigmoid(float x) {
    return __builtin_amdgcn_rcpf(1.f + __expf(-x));
}

// ---- fused prep: Wt | Wpq | Wca | Wenc | Sb | x->Abuf ----
__global__ __launch_bounds__(256) void k_prep(
    const float* __restrict__ out_W, const float* __restrict__ core_W,
    const float* __restrict__ ctx_W, const float* __restrict__ att_W1,
    const float* __restrict__ enc_W, const float* __restrict__ state,
    const float* __restrict__ x,
    ushort_t* __restrict__ Wt, ushort_t* __restrict__ Wpq,
    ushort_t* __restrict__ Wca, ushort_t* __restrict__ Wenc,
    ushort_t* __restrict__ Sb, ushort_t* __restrict__ Abuf)
{
    const int b = blockIdx.x, t = threadIdx.x;
    if (b < 256) {                      // Wt[n][k] = out_W[k][n]
        const int n = b;
        for (int k = t; k < KP; k += 256) {
            const float v = (n < H && k < 1076) ? out_W[(size_t)k * H + n] : 0.f;
            Wt[(size_t)n * KP + k] = f2bf(v);
        }
    } else if (b < 768) {               // Wpq
        const int n = b - 256, k = t;
        float v = 0.f;
        if (k < H) {
            if (n < H)                    v = core_W[(size_t)k * H + n];
            else if (n >= 256 && n < 506) v = core_W[(size_t)(H + k) * H + (n - 256)];
        }
        Wpq[(size_t)n * 256 + k] = f2bf(v);
    } else if (b < 1152) {              // Wca
        const int n = b - 768, k = t;
        float v = 0.f;
        if (k < H) {
            if (n < H)           v = ctx_W[(size_t)k * H + n];
            else if (n < H + HA) v = att_W1[(size_t)k * HA + (n - H)];
        }
        Wca[(size_t)n * 256 + k] = f2bf(v);
    } else if (b < 1408) {              // Wenc[n][k] = enc_W[k][n]
        const int n = b - 1152, k = t;
        const float v = (n < H && k < H) ? enc_W[(size_t)k * H + n] : 0.f;
        Wenc[(size_t)n * 256 + k] = f2bf(v);
    } else if (b < 2432) {              // Sb: state padded to 256, bf16
        const int r0 = (b - 1408) * 16;
        for (int idx = t; idx < 16 * 256; idx += 256) {
            const int r = r0 + (idx >> 8), k = idx & 255;
            const float v = (k < H) ? state[(size_t)r * H + k] : 0.f;
            Sb[(size_t)r * 256 + k] = f2bf(v);
        }
    } else {                            // Abuf cols [500,1088): x + pad
        const int row = b - 2432;
        for (int c = 500 + t; c < KP; c += 256) {
            const float v = (c < 500 + MDIM) ? x[(size_t)row * MDIM + (c - 500)] : 0.f;
            Abuf[(size_t)row * KP + c] = f2bf(v);
        }
    }
}

// N-resident bf16 MFMA GEMM (k_cs-style): C[m][n] = sum_k A[m][k]*B[n][k] (+bias)
// Whole N = NT*64 resident in LDS per block -> A fetched exactly once.
// 512 thr = 8 waves (2m x 4n); per wave 32 rows x NT*16 cols; acc[2][NT].
template<int NT>
__global__ __launch_bounds__(512, NT == 8 ? 2 : 4) void k_gemm_nres(
    const ushort_t* __restrict__ A, int lda,
    const ushort_t* __restrict__ B, int ldb,
    void* __restrict__ Cp, int ldc,
    const float* __restrict__ bias,
    int ksteps, int nlim, int bf16out)
{
    constexpr int NROWS = NT * 64;                    // B rows resident
    __shared__ __align__(16) ushort_t As[64 * 32];    // 4 KB
    __shared__ __align__(16) ushort_t Bs[NROWS * 32]; // NT*4 KB
    const int tid = threadIdx.x, lane = tid & 63, wave = tid >> 6;
    const int wm = wave >> 2, wn = wave & 3;
    const int R0 = (int)blockIdx.x * 64;

    const int ar = tid >> 2, acb = tid & 3;
    const bool aon = tid < 256;
    const int acl = acb ^ ((ar >> 1) & 3);
    const ushort_t* gA = A + (size_t)(R0 + ar) * lda + acl * 8;

    const int q = lane >> 4, fr = lane & 15;

    f32x4 acc[2][NT] = {};
    for (int ks = 0; ks < ksteps; ++ks) {
        const int k0 = ks * 32;
        if (aon) async_copy16(gA + k0, &As[tid * 8]);
#pragma unroll
        for (int it = 0; it < NT / 2; ++it) {
            const int ci  = it * 512 + tid;
            const int rb  = ci >> 2, cb2 = ci & 3;
            const int clb = cb2 ^ ((rb >> 1) & 3);
            async_copy16(B + (size_t)rb * ldb + k0 + clb * 8, &Bs[ci * 8]);
        }
        __syncthreads();
        short8 a[2];
#pragma unroll
        for (int ms = 0; ms < 2; ++ms) {
            const int row = wm * 32 + ms * 16 + fr;
            a[ms] = *(const short8*)&As[(row * 4 + (q ^ ((row >> 1) & 3))) * 8];
        }
#pragma unroll
        for (int nt = 0; nt < NT; ++nt) {
            const int n = wn * (NT * 16) + nt * 16 + fr;
            const short8 b = *(const short8*)&Bs[(n * 4 + (q ^ ((n >> 1) & 3))) * 8];
#pragma unroll
            for (int ms = 0; ms < 2; ++ms)
                acc[ms][nt] = __builtin_amdgcn_mfma_f32_16x16x32_bf16(
                    a[ms], b, acc[ms][nt], 0, 0, 0);
        }
        __syncthreads();
    }

#pragma unroll
    for (int ms = 0; ms < 2; ++ms)
#pragma unroll
        for (int nt = 0; nt < NT; ++nt) {
            const int col = wn * (NT * 16) + nt * 16 + fr;
            if (col >= nlim) continue;
            const float bv = bias ? bias[col] : 0.f;
#pragma unroll
            for (int reg = 0; reg < 4; ++reg) {
                const int row = R0 + wm * 32 + ms * 16 + q * 4 + reg;
                const float v = acc[ms][nt][reg] + bv;
                if (bf16out) ((ushort_t*)Cp)[(size_t)row * ldc + col] = f2bf(v);
                else         ((float*)Cp)[(size_t)row * ldc + col] = v;
            }
        }
}

// LN(relu(Epre + enc_b)) -> Abuf cols [0,250). One wave per row, us4 loads.
__global__ __launch_bounds__(256) void k_lnenc(const ushort_t* __restrict__ Epre,
    const float* __restrict__ eb, const float* __restrict__ eg,
    const float* __restrict__ ebt, ushort_t* __restrict__ Abuf)
{
    const int wave = threadIdx.x >> 6, lane = threadIdx.x & 63;
    const int row = blockIdx.x * 4 + wave;
    const int c0 = 4 * lane;

    const us4 v = *(const us4*)&Epre[(size_t)row * 256 + c0];
    float y[4]; float sm = 0.f, sq = 0.f;
#pragma unroll
    for (int t = 0; t < 4; ++t) {
        const int cc = c0 + t;
        float z = 0.f;
        if (cc < H) z = fmaxf(bf2f(v[t]) + eb[cc], 0.f);
        y[t] = z; sm += z; sq += z * z;
    }
    sm = wave_sum_dpp(sm);
    sq = wave_sum_dpp(sq);
    const float mu = sm * (1.f / H);
    const float rs = __builtin_amdgcn_rsqf(sq * (1.f / H) - mu * mu + EPS);
    ushort_t o[4];
#pragma unroll
    for (int t = 0; t < 4; ++t) {
        const int cc = c0 + t;
        o[t] = (cc < H) ? f2bf((y[t] - mu) * rs * eg[cc] + ebt[cc]) : (ushort_t)0;
    }
    ushort_t* dst = Abuf + (size_t)row * KP + c0;
    if (c0 + 3 < H) { *(us4*)dst = (us4){o[0], o[1], o[2], o[3]}; }
    else {
        if (c0 + 1 < H) *(us2*)dst = (us2){o[0], o[1]};
    }
}

// ================= mega-fused core+cs+eff =================
// Block = 32 groups. Loop jj=0..6: build A in LDS (k_core LN), GEMM vs Wca
// (k_cs staging), gated-accumulate into LDS effacc (spill-free: the cross-jj
// accumulators A4/S0/S1 live in LDS, not VGPRs — round-3's 113 MB scratch
// write traffic came from the arch-VGPR half (64) overflowing).
__global__ __launch_bounds__(512, 4) void k_fuse(
    const ushort_t* __restrict__ PQb,
    const ushort_t* __restrict__ Wca,   // [384][256] bf16
    const float* __restrict__ core_b, const float* __restrict__ core_g,
    const float* __restrict__ core_bt,
    const float* __restrict__ ctx_b, const float* __restrict__ ctx_g,
    const float* __restrict__ ctx_bt,
    const float* __restrict__ att_b1, const float* __restrict__ att_g,
    const float* __restrict__ att_bt,
    const float* __restrict__ attW2, const float* __restrict__ att_b2,
    ushort_t* __restrict__ Abuf)
{
    __shared__ __align__(16) ushort_t As[32 * 256];  // 16 KB, slot-swizzled
    __shared__ __align__(16) ushort_t Bs[384 * 32];  // 24 KB per k-step
    __shared__ __align__(16) float red[32][36];      // [row][wn*8 + v]
    __shared__ __align__(16) float effacc[32 * EFS]; // 33 KB cross-jj accum
    __shared__ float scal[32];                       // per-row cj (per jj)
    __shared__ float sS0[32], sS1[32];               // cross-jj row scalars
    __shared__ float swred[4][2];

    const int tid = threadIdx.x, lane = tid & 63, wave = tid >> 6;
    const int wm = wave >> 2, wn = wave & 3;
    const int q = lane >> 4, fr = lane & 15;
    const int g0 = (int)blockIdx.x * 32;

    // ---- per-lane per-col constants for the 6 nt tiles (epilogue) ----
    bool eC[6], eA[6];
    float b_[6], gw[6];
    float psgw = 0.f, psbw = 0.f;
#pragma unroll
    for (int nt = 0; nt < 6; ++nt) {
        const int col = wn * 96 + nt * 16 + fr;
        eC[nt] = col < H;
        eA[nt] = (col >= H) && (col < H + HA);
        if (eC[nt]) {
            b_[nt] = ctx_b[col]; gw[nt] = 0.f;
        } else if (eA[nt]) {
            const int ca = col - H;
            b_[nt] = att_b1[ca];
            const float ga = att_g[ca], w2 = attW2[ca];
            gw[nt] = ga * w2;
            psgw += gw[nt]; psbw += att_bt[ca] * w2;
        } else {
            b_[nt] = gw[nt] = 0.f;
        }
    }
    // row-invariant attention sums (fr-butterfly + cross-wave via LDS)
    psgw = bfly16_sum(psgw); psbw = bfly16_sum(psbw);
    if (lane == 0) { swred[wn][0] = psgw; swred[wn][1] = psbw; }  // wm dup: benign
    // zero the cross-jj LDS accumulators
    for (int i = tid; i < 32 * EFS; i += 512) effacc[i] = 0.f;
    if (wave == 0 && lane < 32) { sS0[lane] = 0.f; sS1[lane] = 0.f; }
    __syncthreads();
    const float sgw = swred[0][0] + swred[1][0] + swred[2][0] + swred[3][0];
    const float ab2 = att_b2[0] +
        (swred[0][1] + swred[1][1] + swred[2][1] + swred[3][1]);

    // ---- phase-1 jj-invariant state: lane's 4 cols ----
    const int cL = lane * 4;
    float cb4[4], cg4[4], cbt4[4]; bool vl4[4];
#pragma unroll
    for (int t = 0; t < 4; ++t) {
        vl4[t] = (cL + t) < H;
        cb4[t] = cg4[t] = cbt4[t] = 0.f;
        if (vl4[t]) { cb4[t] = core_b[cL + t]; cg4[t] = core_g[cL + t];
                      cbt4[t] = core_bt[cL + t]; }
    }

    // GEMM A-read addressing
    const int arow = wm * 16 + fr;
    const int abase = arow * 256;
    const int arsw = arow & 7;

    for (int jj = 0; jj < 7; ++jj) {
        // ---- phase 1: build A rows = LN(relu(P+Q+core_b)), wave-per-row ----
#pragma unroll
        for (int pass = 0; pass < 4; ++pass) {
            const int r = pass * 8 + wave;
            const int ir = r & 7;
            const int j = jj + (jj >= ir ? 1 : 0);
            const us4 pu = *(const us4*)&PQb[(size_t)(g0 + r) * PQS + cL];
            const us4 qu = *(const us4*)&PQb[
                (size_t)(g0 + (r & ~7) + j) * PQS + 256 + cL];
            float z[4]; float sm = 0.f, sq = 0.f;
#pragma unroll
            for (int t = 0; t < 4; ++t) {
                float zz = 0.f;
                if (vl4[t]) zz = fmaxf(bf2f(pu[t]) + bf2f(qu[t]) + cb4[t], 0.f);
                z[t] = zz; sm += zz; sq = fmaf(zz, zz, sq);
            }
            sm = wave_sum_dpp(sm);
            sq = wave_sum_dpp(sq);
            const float mu = sm * (1.f / H);
            const float rs = __builtin_amdgcn_rsqf(sq * (1.f / H) - mu * mu + EPS);
            us4 o;
#pragma unroll
            for (int t = 0; t < 4; ++t)
                o[t] = vl4[t] ? f2bf((z[t] - mu) * rs * cg4[t] + cbt4[t])
                              : (ushort_t)0;
            const int p = (((lane >> 1) ^ (r & 7)) << 1) | (lane & 1);
            *(us4*)&As[r * 256 + p * 4] = o;
        }

        // ---- phase 2: GEMM M=32 N=384 K=256 (uniform per-ks staging) ----
        f32x4 acc[6] = {};
        for (int ks = 0; ks < 8; ++ks) {
#pragma unroll
            for (int it = 0; it < 3; ++it) {
                const int ci  = it * 512 + tid;
                const int rb  = ci >> 2, cb2 = ci & 3;
                const int clb = cb2 ^ ((rb >> 1) & 3);
                async_copy16(Wca + (size_t)rb * 256 + ks * 32 + clb * 8, &Bs[ci * 8]);
            }
            __syncthreads();   // Bs(ks) staged; As ready (jj's ds_writes drained)
            const short8 a = *(const short8*)&As[abase + ((ks * 4 + q) ^ arsw) * 8];
#pragma unroll
            for (int nt = 0; nt < 6; ++nt) {
                const int n = wn * 96 + nt * 16 + fr;
                const short8 b = *(const short8*)&Bs[(n * 4 + (q ^ ((n >> 1) & 3))) * 8];
                acc[nt] = __builtin_amdgcn_mfma_f32_16x16x32_bf16(a, b, acc[nt], 0, 0, 0);
            }
            __syncthreads();   // Bs reads done
        }

        // ---- phase 3: transform + per-row reductions + gate ----
        float smc[4] = {}, sqc[4] = {}, sma[4] = {}, sqa[4] = {}, szgw[4] = {};
#pragma unroll
        for (int nt = 0; nt < 6; ++nt) {
#pragma unroll
            for (int reg = 0; reg < 4; ++reg) {
                const float val = acc[nt][reg] + b_[nt];
                if (eC[nt]) {
                    const float zz = fmaxf(val, 0.f);
                    acc[nt][reg] = zz;
                    smc[reg] += zz; sqc[reg] = fmaf(zz, zz, sqc[reg]);
                } else if (eA[nt]) {
                    const float za = ftanh(val);
                    sma[reg] += za; sqa[reg] = fmaf(za, za, sqa[reg]);
                    szgw[reg] = fmaf(za, gw[nt], szgw[reg]);
                }
            }
        }
#pragma unroll
        for (int reg = 0; reg < 4; ++reg) {
            smc[reg]  = bfly16_sum(smc[reg]);
            sqc[reg]  = bfly16_sum(sqc[reg]);
            sma[reg]  = bfly16_sum(sma[reg]);
            sqa[reg]  = bfly16_sum(sqa[reg]);
            szgw[reg] = bfly16_sum(szgw[reg]);
        }
        if (fr == 0) {
#pragma unroll
            for (int reg = 0; reg < 4; ++reg) {
                const int row = wm * 16 + q * 4 + reg;
                *(f32x4*)&red[row][wn * 8] =
                    (f32x4){smc[reg], sqc[reg], sma[reg], sqa[reg]};
                red[row][wn * 8 + 4] = szgw[reg];
            }
        }
        __syncthreads();
        if (wave == 0 && lane < 32) {
            const int rr = lane;
            float s0 = 0.f, s1 = 0.f, s2 = 0.f, s3 = 0.f, s4 = 0.f;
#pragma unroll
            for (int w2 = 0; w2 < 4; ++w2) {
                const f32x4 v = *(const f32x4*)&red[rr][w2 * 8];
                s0 += v[0]; s1 += v[1]; s2 += v[2]; s3 += v[3];
                s4 += red[rr][w2 * 8 + 4];
            }
            const float muC = s0 * (1.f / H);
            const float rsC = __builtin_amdgcn_rsqf(s1 * (1.f / H) - muC * muC + EPS);
            const float muA = s2 * (1.f / HA);
            const float rsA = __builtin_amdgcn_rsqf(s3 * (1.f / HA) - muA * muA + EPS);
            const float dot = rsA * (s4 - muA * sgw) + ab2;
            const float ag  = fsigmoid(dot);
            const float cj  = ag * rsC;
            scal[rr] = cj;
            sS0[rr] += ag;
            sS1[rr] = fmaf(cj, muC, sS1[rr]);
        }
        __syncthreads();
        // gated accumulate into LDS (unique owner per (row,col) -> plain RMW)
#pragma unroll
        for (int reg = 0; reg < 4; ++reg) {
            const int row = wm * 16 + q * 4 + reg;
            const float cj = scal[row];
#pragma unroll
            for (int nt = 0; nt < 6; ++nt) {
                if (!eC[nt]) continue;
                const int col = wn * 96 + nt * 16 + fr;
                const int idx = row * EFS + col;
                effacc[idx] = fmaf(cj, acc[nt][reg], effacc[idx]);
            }
        }
    } // jj

    // ---- final write: eff -> Abuf cols [250, 500) ----
#pragma unroll
    for (int nt = 0; nt < 6; ++nt) {
        const int col = wn * 96 + nt * 16 + fr;
        if (col >= H) continue;
        const float gc = ctx_g[col], bc = ctx_bt[col];
#pragma unroll
        for (int reg = 0; reg < 4; ++reg) {
            const int row = wm * 16 + q * 4 + reg;
            const float a4 = effacc[row * EFS + col];
            const float o = gc * (a4 - sS1[row]) + bc * sS0[row];
            Abuf[(size_t)(g0 + row) * KP + H + col] = f2bf(o);
        }
    }
}

extern "C" void kernel_launch(void* const* d_in, const int* in_sizes, int n_in,
                              void* d_out, int out_size, void* d_ws, size_t ws_size,
                              hipStream_t stream)
{
    const float* x      = (const float*)d_in[0];
    const float* state  = (const float*)d_in[1];
    const float* enc_W  = (const float*)d_in[2];
    const float* enc_b  = (const float*)d_in[3];
    const float* enc_g  = (const float*)d_in[4];
    const float* enc_bt = (const float*)d_in[5];
    const float* core_W = (const float*)d_in[6];
    const float* core_b = (const float*)d_in[7];
    const float* core_g = (const float*)d_in[8];
    const float* core_bt= (const float*)d_in[9];
    const float* ctx_W  = (const float*)d_in[10];
    const float* ctx_b  = (const float*)d_in[11];
    const float* ctx_g  = (const float*)d_in[12];
    const float* ctx_bt = (const float*)d_in[13];
    const float* att_W1 = (const float*)d_in[14];
    const float* att_b1 = (const float*)d_in[15];
    const float* att_g  = (const float*)d_in[16];
    const float* att_bt = (const float*)d_in[17];
    const float* att_W2 = (const float*)d_in[18];
    const float* att_b2 = (const float*)d_in[19];
    const float* out_W  = (const float*)d_in[20];
    const float* out_b  = (const float*)d_in[21];
    float* out = (float*)d_out;

    // workspace layout (ushort units) — Co/Cs eliminated by k_fuse
    ushort_t* Abuf = (ushort_t*)d_ws;                   // 16384*1088  (35.7 MB)
    ushort_t* Wt   = Abuf + (size_t)ROWS * KP;          // 256*1088
    ushort_t* Wpq  = Wt + (size_t)256 * KP;             // 512*256
    ushort_t* Wca  = Wpq + (size_t)512 * 256;           // 384*256
    ushort_t* Wenc = Wca + (size_t)384 * 256;           // 256*256
    ushort_t* Sb   = Wenc + (size_t)256 * 256;          // 16384*256   (8 MB)
    ushort_t* Epre = Sb + (size_t)ROWS * 256;           // 16384*256   (8 MB)
    ushort_t* PQb  = Epre + (size_t)ROWS * 256;         // 16384*512   (16 MB)

    k_prep  <<<2432 + ROWS, 256, 0, stream>>>(out_W, core_W, ctx_W, att_W1, enc_W,
                                              state, x, Wt, Wpq, Wca, Wenc, Sb, Abuf);
    // Epre = state @ enc_W  (bf16 MFMA, N=256 resident)
    k_gemm_nres<4><<<ROWS / 64, 512, 0, stream>>>(Sb, 256, Wenc, 256, Epre, 256,
                                                  nullptr, 8, 256, 1);
    k_lnenc <<<ROWS / 4, 256, 0, stream>>>(Epre, enc_b, enc_g, enc_bt, Abuf);
    // PQb = s1 @ [W_top | W_bot]  (bf16 MFMA, N=512 resident, bf16 out)
    k_gemm_nres<8><<<ROWS / 64, 512, 0, stream>>>(Abuf, KP, Wpq, 256, PQb, PQS,
                                                  nullptr, 8, 512, 1);
    // fused core -> cs -> eff
    k_fuse  <<<ROWS / 32, 512, 0, stream>>>(PQb, Wca,
                                            core_b, core_g, core_bt,
                                            ctx_b, ctx_g, ctx_bt,
                                            att_b1, att_g, att_bt,
                                            att_W2, att_b2, Abuf);
    // out = [s1 | eff | x] @ out_W + b  (bf16 MFMA, N=256 resident, fp32 out)
    k_gemm_nres<4><<<ROWS / 64, 512, 0, stream>>>(Abuf, KP, Wt, KP, out, H,
                                                  out_b, KP / 32, 250, 0);
}

// Round 5
// 348.193 us; speedup vs baseline: 1.3384x; 1.0902x over previous
//
#include <hip/hip_runtime.h>
#include <math.h>

#define KK 8
#define H 250          // SIZE == h1
#define MDIM 576
#define NB 2048
#define HA 100
#define ROWS (NB*KK)   // 16384
#define PQS 512        // PQb row stride (ushort): P at 0..249, Q at 256..505
#define KP 1088        // padded K for out GEMM (1076 -> 34*32)
#define EFS 258        // effacc row stride (f32): 256+2 -> q-rows 8 banks apart
#define EPS 1e-5f

typedef unsigned short ushort_t;
typedef short short8 __attribute__((ext_vector_type(8)));
typedef unsigned short us8 __attribute__((ext_vector_type(8)));
typedef unsigned short us4 __attribute__((ext_vector_type(4)));
typedef unsigned short us2 __attribute__((ext_vector_type(2)));
typedef float f32x4 __attribute__((ext_vector_type(4)));

// ---- DPP helpers (old=0 + bound_ctrl=1 so GCNDPPCombine folds to v_add_f32_dpp) ----
template<int CTRL>
__device__ __forceinline__ float dpp_add_f32(float x) {
    const int s = __builtin_amdgcn_update_dpp(
        0, __builtin_bit_cast(int, x), CTRL, 0xF, 0xF, true);
    return x + __builtin_bit_cast(float, s);
}
// full-wave (64-lane) sum; result broadcast wave-uniform via readlane(63)
__device__ __forceinline__ float wave_sum_dpp(float x) {
    x = dpp_add_f32<0x111>(x);  // row_shr:1
    x = dpp_add_f32<0x112>(x);  // row_shr:2
    x = dpp_add_f32<0x114>(x);  // row_shr:4
    x = dpp_add_f32<0x118>(x);  // row_shr:8
    x = dpp_add_f32<0x142>(x);  // row_bcast:15
    x = dpp_add_f32<0x143>(x);  // row_bcast:31 -> lane 63 holds total
    return __builtin_bit_cast(float, __builtin_amdgcn_readlane(
        __builtin_bit_cast(int, x), 63));
}
// 16-lane butterfly sum: result present in ALL 16 lanes of each 16-lane row
__device__ __forceinline__ float bfly16_sum(float x) {
    x = dpp_add_f32<0xB1>(x);   // quad_perm [1,0,3,2]  (xor 1)
    x = dpp_add_f32<0x4E>(x);   // quad_perm [2,3,0,1]  (xor 2)
    x = dpp_add_f32<0x141>(x);  // row_half_mirror      (pairs across quads)
    x = dpp_add_f32<0x140>(x);  // row_mirror           (pairs across halves)
    return x;
}

__device__ __forceinline__ void async_copy16(const void* g, void* l) {
    __builtin_amdgcn_global_load_lds(
        (const __attribute__((address_space(1))) void*)g,
        (__attribute__((address_space(3))) void*)l, 16, 0, 0);
}

__device__ __forceinline__ ushort_t f2bf(float v) {
    union { float f; unsigned int u; } c; c.f = v;
    unsigned int x = c.u;
    x += 0x7fff + ((x >> 16) & 1);   // RNE
    return (ushort_t)(x >> 16);
}
__device__ __forceinline__ float bf2f(ushort_t v) {
    union { unsigned int u; float f; } c; c.u = ((unsigned int)v) << 16;
    return c.f;
}
// fast tanh: 1 - 2/(exp(2x)+1)  (v_exp + v_rcp; ~1e-6 rel err, << bf16 ulp)
__device__ __forceinline__ float ftanh(float x) {
    const float e = __expf(2.f * x);
    return 1.f - 2.f * __builtin_amdgcn_rcpf(e + 1.f);
}
__device__ __forceinline__ float fsigmoid(float x) {
    return __builtin_amdgcn_rcpf(1.f + __expf(-x));
}

// ---- fused prep: Wt | Wpq | Wca | Wenc | Sb | x->Abuf ----
__global__ __launch_bounds__(256) void k_prep(
    const float* __restrict__ out_W, const float* __restrict__ core_W,
    const float* __restrict__ ctx_W, const float* __restrict__ att_W1,
    const float* __restrict__ enc_W, const float* __restrict__ state,
    const float* __restrict__ x,
    ushort_t* __restrict__ Wt, ushort_t* __restrict__ Wpq,
    ushort_t* __restrict__ Wca, ushort_t* __restrict__ Wenc,
    ushort_t* __restrict__ Sb, ushort_t* __restrict__ Abuf)
{
    const int b = blockIdx.x, t = threadIdx.x;
    if (b < 256) {                      // Wt[n][k] = out_W[k][n]
        const int n = b;
        for (int k = t; k < KP; k += 256) {
            const float v = (n < H && k < 1076) ? out_W[(size_t)k * H + n] : 0.f;
            Wt[(size_t)n * KP + k] = f2bf(v);
        }
    } else if (b < 768) {               // Wpq
        const int n = b - 256, k = t;
        float v = 0.f;
        if (k < H) {
            if (n < H)                    v = core_W[(size_t)k * H + n];
            else if (n >= 256 && n < 506) v = core_W[(size_t)(H + k) * H + (n - 256)];
        }
        Wpq[(size_t)n * 256 + k] = f2bf(v);
    } else if (b < 1152) {              // Wca
        const int n = b - 768, k = t;
        float v = 0.f;
        if (k < H) {
            if (n < H)           v = ctx_W[(size_t)k * H + n];
            else if (n < H + HA) v = att_W1[(size_t)k * HA + (n - H)];
        }
        Wca[(size_t)n * 256 + k] = f2bf(v);
    } else if (b < 1408) {              // Wenc[n][k] = enc_W[k][n]
        const int n = b - 1152, k = t;
        const float v = (n < H && k < H) ? enc_W[(size_t)k * H + n] : 0.f;
        Wenc[(size_t)n * 256 + k] = f2bf(v);
    } else if (b < 2432) {              // Sb: state padded to 256, bf16
        const int r0 = (b - 1408) * 16;
        for (int idx = t; idx < 16 * 256; idx += 256) {
            const int r = r0 + (idx >> 8), k = idx & 255;
            const float v = (k < H) ? state[(size_t)r * H + k] : 0.f;
            Sb[(size_t)r * 256 + k] = f2bf(v);
        }
    } else {                            // Abuf cols [500,1088): x + pad
        const int row = b - 2432;
        for (int c = 500 + t; c < KP; c += 256) {
            const float v = (c < 500 + MDIM) ? x[(size_t)row * MDIM + (c - 500)] : 0.f;
            Abuf[(size_t)row * KP + c] = f2bf(v);
        }
    }
}

// N-resident bf16 MFMA GEMM (k_cs-style): C[m][n] = sum_k A[m][k]*B[n][k] (+bias)
// Whole N = NT*64 resident in LDS per block -> A fetched exactly once.
// 512 thr = 8 waves (2m x 4n); per wave 32 rows x NT*16 cols; acc[2][NT].
template<int NT>
__global__ __launch_bounds__(512, NT == 8 ? 2 : 4) void k_gemm_nres(
    const ushort_t* __restrict__ A, int lda,
    const ushort_t* __restrict__ B, int ldb,
    void* __restrict__ Cp, int ldc,
    const float* __restrict__ bias,
    int ksteps, int nlim, int bf16out)
{
    constexpr int NROWS = NT * 64;                    // B rows resident
    __shared__ __align__(16) ushort_t As[64 * 32];    // 4 KB
    __shared__ __align__(16) ushort_t Bs[NROWS * 32]; // NT*4 KB
    const int tid = threadIdx.x, lane = tid & 63, wave = tid >> 6;
    const int wm = wave >> 2, wn = wave & 3;
    const int R0 = (int)blockIdx.x * 64;

    const int ar = tid >> 2, acb = tid & 3;
    const bool aon = tid < 256;
    const int acl = acb ^ ((ar >> 1) & 3);
    const ushort_t* gA = A + (size_t)(R0 + ar) * lda + acl * 8;

    const int q = lane >> 4, fr = lane & 15;

    f32x4 acc[2][NT] = {};
    for (int ks = 0; ks < ksteps; ++ks) {
        const int k0 = ks * 32;
        if (aon) async_copy16(gA + k0, &As[tid * 8]);
#pragma unroll
        for (int it = 0; it < NT / 2; ++it) {
            const int ci  = it * 512 + tid;
            const int rb  = ci >> 2, cb2 = ci & 3;
            const int clb = cb2 ^ ((rb >> 1) & 3);
            async_copy16(B + (size_t)rb * ldb + k0 + clb * 8, &Bs[ci * 8]);
        }
        __syncthreads();
        short8 a[2];
#pragma unroll
        for (int ms = 0; ms < 2; ++ms) {
            const int row = wm * 32 + ms * 16 + fr;
            a[ms] = *(const short8*)&As[(row * 4 + (q ^ ((row >> 1) & 3))) * 8];
        }
#pragma unroll
        for (int nt = 0; nt < NT; ++nt) {
            const int n = wn * (NT * 16) + nt * 16 + fr;
            const short8 b = *(const short8*)&Bs[(n * 4 + (q ^ ((n >> 1) & 3))) * 8];
#pragma unroll
            for (int ms = 0; ms < 2; ++ms)
                acc[ms][nt] = __builtin_amdgcn_mfma_f32_16x16x32_bf16(
                    a[ms], b, acc[ms][nt], 0, 0, 0);
        }
        __syncthreads();
    }

#pragma unroll
    for (int ms = 0; ms < 2; ++ms)
#pragma unroll
        for (int nt = 0; nt < NT; ++nt) {
            const int col = wn * (NT * 16) + nt * 16 + fr;
            if (col >= nlim) continue;
            const float bv = bias ? bias[col] : 0.f;
#pragma unroll
            for (int reg = 0; reg < 4; ++reg) {
                const int row = R0 + wm * 32 + ms * 16 + q * 4 + reg;
                const float v = acc[ms][nt][reg] + bv;
                if (bf16out) ((ushort_t*)Cp)[(size_t)row * ldc + col] = f2bf(v);
                else         ((float*)Cp)[(size_t)row * ldc + col] = v;
            }
        }
}

// LN(relu(Epre + enc_b)) -> Abuf cols [0,250). One wave per row, us4 loads.
__global__ __launch_bounds__(256) void k_lnenc(const ushort_t* __restrict__ Epre,
    const float* __restrict__ eb, const float* __restrict__ eg,
    const float* __restrict__ ebt, ushort_t* __restrict__ Abuf)
{
    const int wave = threadIdx.x >> 6, lane = threadIdx.x & 63;
    const int row = blockIdx.x * 4 + wave;
    const int c0 = 4 * lane;

    const us4 v = *(const us4*)&Epre[(size_t)row * 256 + c0];
    float y[4]; float sm = 0.f, sq = 0.f;
#pragma unroll
    for (int t = 0; t < 4; ++t) {
        const int cc = c0 + t;
        float z = 0.f;
        if (cc < H) z = fmaxf(bf2f(v[t]) + eb[cc], 0.f);
        y[t] = z; sm += z; sq += z * z;
    }
    sm = wave_sum_dpp(sm);
    sq = wave_sum_dpp(sq);
    const float mu = sm * (1.f / H);
    const float rs = __builtin_amdgcn_rsqf(sq * (1.f / H) - mu * mu + EPS);
    ushort_t o[4];
#pragma unroll
    for (int t = 0; t < 4; ++t) {
        const int cc = c0 + t;
        o[t] = (cc < H) ? f2bf((y[t] - mu) * rs * eg[cc] + ebt[cc]) : (ushort_t)0;
    }
    ushort_t* dst = Abuf + (size_t)row * KP + c0;
    if (c0 + 3 < H) { *(us4*)dst = (us4){o[0], o[1], o[2], o[3]}; }
    else {
        if (c0 + 1 < H) *(us2*)dst = (us2){o[0], o[1]};
    }
}

// ================= mega-fused core+cs+eff =================
// Block = 32 groups. Loop jj=0..6: build A in LDS (k_core LN), GEMM vs Wca
// (k_cs staging), gated-accumulate into LDS effacc. Cross-jj accumulators
// live in LDS. __launch_bounds__(512, 2): 256 unified VGPR/wave — round-4's
// (512,4)=128 budget forced a 64-arch split and ~180 MB/launch scratch
// spill traffic (WRITE_SIZE 72 MB vs legit 9 MB).
__global__ __launch_bounds__(512, 2) void k_fuse(
    const ushort_t* __restrict__ PQb,
    const ushort_t* __restrict__ Wca,   // [384][256] bf16
    const float* __restrict__ core_b, const float* __restrict__ core_g,
    const float* __restrict__ core_bt,
    const float* __restrict__ ctx_b, const float* __restrict__ ctx_g,
    const float* __restrict__ ctx_bt,
    const float* __restrict__ att_b1, const float* __restrict__ att_g,
    const float* __restrict__ att_bt,
    const float* __restrict__ attW2, const float* __restrict__ att_b2,
    ushort_t* __restrict__ Abuf)
{
    __shared__ __align__(16) ushort_t As[32 * 256];  // 16 KB, slot-swizzled
    __shared__ __align__(16) ushort_t Bs[384 * 32];  // 24 KB per k-step
    __shared__ __align__(16) float red[32][36];      // [row][wn*8 + v]
    __shared__ __align__(16) float effacc[32 * EFS]; // 33 KB cross-jj accum
    __shared__ float scal[32];                       // per-row cj (per jj)
    __shared__ float sS0[32], sS1[32];               // cross-jj row scalars
    __shared__ float swred[4][2];

    const int tid = threadIdx.x, lane = tid & 63, wave = tid >> 6;
    const int wm = wave >> 2, wn = wave & 3;
    const int q = lane >> 4, fr = lane & 15;
    const int g0 = (int)blockIdx.x * 32;

    // ---- per-lane per-col constants for the 6 nt tiles (epilogue) ----
    bool eC[6], eA[6];
    float b_[6], gw[6];
    float psgw = 0.f, psbw = 0.f;
#pragma unroll
    for (int nt = 0; nt < 6; ++nt) {
        const int col = wn * 96 + nt * 16 + fr;
        eC[nt] = col < H;
        eA[nt] = (col >= H) && (col < H + HA);
        if (eC[nt]) {
            b_[nt] = ctx_b[col]; gw[nt] = 0.f;
        } else if (eA[nt]) {
            const int ca = col - H;
            b_[nt] = att_b1[ca];
            const float ga = att_g[ca], w2 = attW2[ca];
            gw[nt] = ga * w2;
            psgw += gw[nt]; psbw += att_bt[ca] * w2;
        } else {
            b_[nt] = gw[nt] = 0.f;
        }
    }
    // row-invariant attention sums (fr-butterfly + cross-wave via LDS)
    psgw = bfly16_sum(psgw); psbw = bfly16_sum(psbw);
    if (lane == 0) { swred[wn][0] = psgw; swred[wn][1] = psbw; }  // wm dup: benign
    // zero the cross-jj LDS accumulators
    for (int i = tid; i < 32 * EFS; i += 512) effacc[i] = 0.f;
    if (wave == 0 && lane < 32) { sS0[lane] = 0.f; sS1[lane] = 0.f; }
    __syncthreads();
    const float sgw = swred[0][0] + swred[1][0] + swred[2][0] + swred[3][0];
    const float ab2 = att_b2[0] +
        (swred[0][1] + swred[1][1] + swred[2][1] + swred[3][1]);

    // ---- phase-1 jj-invariant state: lane's 4 cols ----
    const int cL = lane * 4;
    float cb4[4], cg4[4], cbt4[4]; bool vl4[4];
#pragma unroll
    for (int t = 0; t < 4; ++t) {
        vl4[t] = (cL + t) < H;
        cb4[t] = cg4[t] = cbt4[t] = 0.f;
        if (vl4[t]) { cb4[t] = core_b[cL + t]; cg4[t] = core_g[cL + t];
                      cbt4[t] = core_bt[cL + t]; }
    }

    // GEMM A-read addressing
    const int arow = wm * 16 + fr;
    const int abase = arow * 256;
    const int arsw = arow & 7;

    for (int jj = 0; jj < 7; ++jj) {
        // ---- phase 1: build A rows = LN(relu(P+Q+core_b)), wave-per-row ----
#pragma unroll
        for (int pass = 0; pass < 4; ++pass) {
            const int r = pass * 8 + wave;
            const int ir = r & 7;
            const int j = jj + (jj >= ir ? 1 : 0);
            const us4 pu = *(const us4*)&PQb[(size_t)(g0 + r) * PQS + cL];
            const us4 qu = *(const us4*)&PQb[
                (size_t)(g0 + (r & ~7) + j) * PQS + 256 + cL];
            float z[4]; float sm = 0.f, sq = 0.f;
#pragma unroll
            for (int t = 0; t < 4; ++t) {
                float zz = 0.f;
                if (vl4[t]) zz = fmaxf(bf2f(pu[t]) + bf2f(qu[t]) + cb4[t], 0.f);
                z[t] = zz; sm += zz; sq = fmaf(zz, zz, sq);
            }
            sm = wave_sum_dpp(sm);
            sq = wave_sum_dpp(sq);
            const float mu = sm * (1.f / H);
            const float rs = __builtin_amdgcn_rsqf(sq * (1.f / H) - mu * mu + EPS);
            us4 o;
#pragma unroll
            for (int t = 0; t < 4; ++t)
                o[t] = vl4[t] ? f2bf((z[t] - mu) * rs * cg4[t] + cbt4[t])
                              : (ushort_t)0;
            const int p = (((lane >> 1) ^ (r & 7)) << 1) | (lane & 1);
            *(us4*)&As[r * 256 + p * 4] = o;
        }

        // ---- phase 2: GEMM M=32 N=384 K=256 (uniform per-ks staging) ----
        f32x4 acc[6] = {};
        for (int ks = 0; ks < 8; ++ks) {
#pragma unroll
            for (int it = 0; it < 3; ++it) {
                const int ci  = it * 512 + tid;
                const int rb  = ci >> 2, cb2 = ci & 3;
                const int clb = cb2 ^ ((rb >> 1) & 3);
                async_copy16(Wca + (size_t)rb * 256 + ks * 32 + clb * 8, &Bs[ci * 8]);
            }
            __syncthreads();   // Bs(ks) staged; As ready (jj's ds_writes drained)
            const short8 a = *(const short8*)&As[abase + ((ks * 4 + q) ^ arsw) * 8];
#pragma unroll
            for (int nt = 0; nt < 6; ++nt) {
                const int n = wn * 96 + nt * 16 + fr;
                const short8 b = *(const short8*)&Bs[(n * 4 + (q ^ ((n >> 1) & 3))) * 8];
                acc[nt] = __builtin_amdgcn_mfma_f32_16x16x32_bf16(a, b, acc[nt], 0, 0, 0);
            }
            __syncthreads();   // Bs reads done
        }

        // ---- phase 3: transform + per-row reductions + gate ----
        float smc[4] = {}, sqc[4] = {}, sma[4] = {}, sqa[4] = {}, szgw[4] = {};
#pragma unroll
        for (int nt = 0; nt < 6; ++nt) {
#pragma unroll
            for (int reg = 0; reg < 4; ++reg) {
                const float val = acc[nt][reg] + b_[nt];
                if (eC[nt]) {
                    const float zz = fmaxf(val, 0.f);
                    acc[nt][reg] = zz;
                    smc[reg] += zz; sqc[reg] = fmaf(zz, zz, sqc[reg]);
                } else if (eA[nt]) {
                    const float za = ftanh(val);
                    sma[reg] += za; sqa[reg] = fmaf(za, za, sqa[reg]);
                    szgw[reg] = fmaf(za, gw[nt], szgw[reg]);
                }
            }
        }
#pragma unroll
        for (int reg = 0; reg < 4; ++reg) {
            smc[reg]  = bfly16_sum(smc[reg]);
            sqc[reg]  = bfly16_sum(sqc[reg]);
            sma[reg]  = bfly16_sum(sma[reg]);
            sqa[reg]  = bfly16_sum(sqa[reg]);
            szgw[reg] = bfly16_sum(szgw[reg]);
        }
        if (fr == 0) {
#pragma unroll
            for (int reg = 0; reg < 4; ++reg) {
                const int row = wm * 16 + q * 4 + reg;
                *(f32x4*)&red[row][wn * 8] =
                    (f32x4){smc[reg], sqc[reg], sma[reg], sqa[reg]};
                red[row][wn * 8 + 4] = szgw[reg];
            }
        }
        __syncthreads();
        if (wave == 0 && lane < 32) {
            const int rr = lane;
            float s0 = 0.f, s1 = 0.f, s2 = 0.f, s3 = 0.f, s4 = 0.f;
#pragma unroll
            for (int w2 = 0; w2 < 4; ++w2) {
                const f32x4 v = *(const f32x4*)&red[rr][w2 * 8];
                s0 += v[0]; s1 += v[1]; s2 += v[2]; s3 += v[3];
                s4 += red[rr][w2 * 8 + 4];
            }
            const float muC = s0 * (1.f / H);
            const float rsC = __builtin_amdgcn_rsqf(s1 * (1.f / H) - muC * muC + EPS);
            const float muA = s2 * (1.f / HA);
            const float rsA = __builtin_amdgcn_rsqf(s3 * (1.f / HA) - muA * muA + EPS);
            const float dot = rsA * (s4 - muA * sgw) + ab2;
            const float ag  = fsigmoid(dot);
            const float cj  = ag * rsC;
            scal[rr] = cj;
            sS0[rr] += ag;
            sS1[rr] = fmaf(cj, muC, sS1[rr]);
        }
        __syncthreads();
        // gated accumulate into LDS (unique owner per (row,col) -> plain RMW)
#pragma unroll
        for (int reg = 0; reg < 4; ++reg) {
            const int row = wm * 16 + q * 4 + reg;
            const float cj = scal[row];
#pragma unroll
            for (int nt = 0; nt < 6; ++nt) {
                if (!eC[nt]) continue;
                const int col = wn * 96 + nt * 16 + fr;
                const int idx = row * EFS + col;
                effacc[idx] = fmaf(cj, acc[nt][reg], effacc[idx]);
            }
        }
    } // jj

    // ---- final write: eff -> Abuf cols [250, 500) ----
#pragma unroll
    for (int nt = 0; nt < 6; ++nt) {
        const int col = wn * 96 + nt * 16 + fr;
        if (col >= H) continue;
        const float gc = ctx_g[col], bc = ctx_bt[col];
#pragma unroll
        for (int reg = 0; reg < 4; ++reg) {
            const int row = wm * 16 + q * 4 + reg;
            const float a4 = effacc[row * EFS + col];
            const float o = gc * (a4 - sS1[row]) + bc * sS0[row];
            Abuf[(size_t)(g0 + row) * KP + H + col] = f2bf(o);
        }
    }
}

extern "C" void kernel_launch(void* const* d_in, const int* in_sizes, int n_in,
                              void* d_out, int out_size, void* d_ws, size_t ws_size,
                              hipStream_t stream)
{
    const float* x      = (const float*)d_in[0];
    const float* state  = (const float*)d_in[1];
    const float* enc_W  = (const float*)d_in[2];
    const float* enc_b  = (const float*)d_in[3];
    const float* enc_g  = (const float*)d_in[4];
    const float* enc_bt = (const float*)d_in[5];
    const float* core_W = (const float*)d_in[6];
    const float* core_b = (const float*)d_in[7];
    const float* core_g = (const float*)d_in[8];
    const float* core_bt= (const float*)d_in[9];
    const float* ctx_W  = (const float*)d_in[10];
    const float* ctx_b  = (const float*)d_in[11];
    const float* ctx_g  = (const float*)d_in[12];
    const float* ctx_bt = (const float*)d_in[13];
    const float* att_W1 = (const float*)d_in[14];
    const float* att_b1 = (const float*)d_in[15];
    const float* att_g  = (const float*)d_in[16];
    const float* att_bt = (const float*)d_in[17];
    const float* att_W2 = (const float*)d_in[18];
    const float* att_b2 = (const float*)d_in[19];
    const float* out_W  = (const float*)d_in[20];
    const float* out_b  = (const float*)d_in[21];
    float* out = (float*)d_out;

    // workspace layout (ushort units) — Co/Cs eliminated by k_fuse
    ushort_t* Abuf = (ushort_t*)d_ws;                   // 16384*1088  (35.7 MB)
    ushort_t* Wt   = Abuf + (size_t)ROWS * KP;          // 256*1088
    ushort_t* Wpq  = Wt + (size_t)256 * KP;             // 512*256
    ushort_t* Wca  = Wpq + (size_t)512 * 256;           // 384*256
    ushort_t* Wenc = Wca + (size_t)384 * 256;           // 256*256
    ushort_t* Sb   = Wenc + (size_t)256 * 256;          // 16384*256   (8 MB)
    ushort_t* Epre = Sb + (size_t)ROWS * 256;           // 16384*256   (8 MB)
    ushort_t* PQb  = Epre + (size_t)ROWS * 256;         // 16384*512   (16 MB)

    k_prep  <<<2432 + ROWS, 256, 0, stream>>>(out_W, core_W, ctx_W, att_W1, enc_W,
                                              state, x, Wt, Wpq, Wca, Wenc, Sb, Abuf);
    // Epre = state @ enc_W  (bf16 MFMA, N=256 resident)
    k_gemm_nres<4><<<ROWS / 64, 512, 0, stream>>>(Sb, 256, Wenc, 256, Epre, 256,
                                                  nullptr, 8, 256, 1);
    k_lnenc <<<ROWS / 4, 256, 0, stream>>>(Epre, enc_b, enc_g, enc_bt, Abuf);
    // PQb = s1 @ [W_top | W_bot]  (bf16 MFMA, N=512 resident, bf16 out)
    k_gemm_nres<8><<<ROWS / 64, 512, 0, stream>>>(Abuf, KP, Wpq, 256, PQb, PQS,
                                                  nullptr, 8, 512, 1);
    // fused core -> cs -> eff
    k_fuse  <<<ROWS / 32, 512, 0, stream>>>(PQb, Wca,
                                            core_b, core_g, core_bt,
                                            ctx_b, ctx_g, ctx_bt,
                                            att_b1, att_g, att_bt,
                                            att_W2, att_b2, Abuf);
    // out = [s1 | eff | x] @ out_W + b  (bf16 MFMA, N=256 resident, fp32 out)
    k_gemm_nres<4><<<ROWS / 64, 512, 0, stream>>>(Abuf, KP, Wt, KP, out, H,
                                                  out_b, KP / 32, 250, 0);
}

// Round 6
// 322.606 us; speedup vs baseline: 1.4445x; 1.0793x over previous
//
#include <hip/hip_runtime.h>
#include <math.h>

#define KK 8
#define H 250          // SIZE == h1
#define MDIM 576
#define NB 2048
#define HA 100
#define ROWS (NB*KK)   // 16384
#define PQS 512        // PQb row stride (ushort): P at 0..249, Q at 256..505
#define KP 1088        // padded K for out GEMM (1076 -> 34*32)
#define EPS 1e-5f

typedef unsigned short ushort_t;
typedef short short8 __attribute__((ext_vector_type(8)));
typedef unsigned short us8 __attribute__((ext_vector_type(8)));
typedef unsigned short us4 __attribute__((ext_vector_type(4)));
typedef unsigned short us2 __attribute__((ext_vector_type(2)));
typedef float f32x4 __attribute__((ext_vector_type(4)));

// ---- DPP helpers (old=0 + bound_ctrl=1 so GCNDPPCombine folds to v_add_f32_dpp) ----
template<int CTRL>
__device__ __forceinline__ float dpp_add_f32(float x) {
    const int s = __builtin_amdgcn_update_dpp(
        0, __builtin_bit_cast(int, x), CTRL, 0xF, 0xF, true);
    return x + __builtin_bit_cast(float, s);
}
// full-wave (64-lane) sum; result broadcast wave-uniform via readlane(63)
__device__ __forceinline__ float wave_sum_dpp(float x) {
    x = dpp_add_f32<0x111>(x);  // row_shr:1
    x = dpp_add_f32<0x112>(x);  // row_shr:2
    x = dpp_add_f32<0x114>(x);  // row_shr:4
    x = dpp_add_f32<0x118>(x);  // row_shr:8
    x = dpp_add_f32<0x142>(x);  // row_bcast:15
    x = dpp_add_f32<0x143>(x);  // row_bcast:31 -> lane 63 holds total
    return __builtin_bit_cast(float, __builtin_amdgcn_readlane(
        __builtin_bit_cast(int, x), 63));
}
// 16-lane butterfly sum: result present in ALL 16 lanes of each 16-lane row
__device__ __forceinline__ float bfly16_sum(float x) {
    x = dpp_add_f32<0xB1>(x);   // quad_perm [1,0,3,2]  (xor 1)
    x = dpp_add_f32<0x4E>(x);   // quad_perm [2,3,0,1]  (xor 2)
    x = dpp_add_f32<0x141>(x);  // row_half_mirror      (pairs across quads)
    x = dpp_add_f32<0x140>(x);  // row_mirror           (pairs across halves)
    return x;
}

__device__ __forceinline__ void async_copy16(const void* g, void* l) {
    __builtin_amdgcn_global_load_lds(
        (const __attribute__((address_space(1))) void*)g,
        (__attribute__((address_space(3))) void*)l, 16, 0, 0);
}

__device__ __forceinline__ ushort_t f2bf(float v) {
    union { float f; unsigned int u; } c; c.f = v;
    unsigned int x = c.u;
    x += 0x7fff + ((x >> 16) & 1);   // RNE
    return (ushort_t)(x >> 16);
}
__device__ __forceinline__ float bf2f(ushort_t v) {
    union { unsigned int u; float f; } c; c.u = ((unsigned int)v) << 16;
    return c.f;
}
// fast tanh: 1 - 2/(exp(2x)+1)  (v_exp + v_rcp; ~1e-6 rel err, << bf16 ulp)
__device__ __forceinline__ float ftanh(float x) {
    const float e = __expf(2.f * x);
    return 1.f - 2.f * __builtin_amdgcn_rcpf(e + 1.f);
}
__device__ __forceinline__ float fsigmoid(float x) {
    return __builtin_amdgcn_rcpf(1.f + __expf(-x));
}

// ---- fused prep: Wt | Wpq | Wca | Wenc | Sb | x->Abuf ----
__global__ __launch_bounds__(256) void k_prep(
    const float* __restrict__ out_W, const float* __restrict__ core_W,
    const float* __restrict__ ctx_W, const float* __restrict__ att_W1,
    const float* __restrict__ enc_W, const float* __restrict__ state,
    const float* __restrict__ x,
    ushort_t* __restrict__ Wt, ushort_t* __restrict__ Wpq,
    ushort_t* __restrict__ Wca, ushort_t* __restrict__ Wenc,
    ushort_t* __restrict__ Sb, ushort_t* __restrict__ Abuf)
{
    const int b = blockIdx.x, t = threadIdx.x;
    if (b < 256) {                      // Wt[n][k] = out_W[k][n]
        const int n = b;
        for (int k = t; k < KP; k += 256) {
            const float v = (n < H && k < 1076) ? out_W[(size_t)k * H + n] : 0.f;
            Wt[(size_t)n * KP + k] = f2bf(v);
        }
    } else if (b < 768) {               // Wpq
        const int n = b - 256, k = t;
        float v = 0.f;
        if (k < H) {
            if (n < H)                    v = core_W[(size_t)k * H + n];
            else if (n >= 256 && n < 506) v = core_W[(size_t)(H + k) * H + (n - 256)];
        }
        Wpq[(size_t)n * 256 + k] = f2bf(v);
    } else if (b < 1152) {              // Wca
        const int n = b - 768, k = t;
        float v = 0.f;
        if (k < H) {
            if (n < H)           v = ctx_W[(size_t)k * H + n];
            else if (n < H + HA) v = att_W1[(size_t)k * HA + (n - H)];
        }
        Wca[(size_t)n * 256 + k] = f2bf(v);
    } else if (b < 1408) {              // Wenc[n][k] = enc_W[k][n]
        const int n = b - 1152, k = t;
        const float v = (n < H && k < H) ? enc_W[(size_t)k * H + n] : 0.f;
        Wenc[(size_t)n * 256 + k] = f2bf(v);
    } else if (b < 2432) {              // Sb: state padded to 256, bf16
        const int r0 = (b - 1408) * 16;
        for (int idx = t; idx < 16 * 256; idx += 256) {
            const int r = r0 + (idx >> 8), k = idx & 255;
            const float v = (k < H) ? state[(size_t)r * H + k] : 0.f;
            Sb[(size_t)r * 256 + k] = f2bf(v);
        }
    } else {                            // Abuf cols [500,1088): x + pad
        const int row = b - 2432;
        for (int c = 500 + t; c < KP; c += 256) {
            const float v = (c < 500 + MDIM) ? x[(size_t)row * MDIM + (c - 500)] : 0.f;
            Abuf[(size_t)row * KP + c] = f2bf(v);
        }
    }
}

// N-resident bf16 MFMA GEMM (k_cs-style): C[m][n] = sum_k A[m][k]*B[n][k] (+bias)
// Whole N = NT*64 resident in LDS per block -> A fetched exactly once.
// 512 thr = 8 waves (2m x 4n); per wave 32 rows x NT*16 cols; acc[2][NT].
template<int NT>
__global__ __launch_bounds__(512, NT == 8 ? 2 : 4) void k_gemm_nres(
    const ushort_t* __restrict__ A, int lda,
    const ushort_t* __restrict__ B, int ldb,
    void* __restrict__ Cp, int ldc,
    const float* __restrict__ bias,
    int ksteps, int nlim, int bf16out)
{
    constexpr int NROWS = NT * 64;                    // B rows resident
    __shared__ __align__(16) ushort_t As[64 * 32];    // 4 KB
    __shared__ __align__(16) ushort_t Bs[NROWS * 32]; // NT*4 KB
    const int tid = threadIdx.x, lane = tid & 63, wave = tid >> 6;
    const int wm = wave >> 2, wn = wave & 3;
    const int R0 = (int)blockIdx.x * 64;

    const int ar = tid >> 2, acb = tid & 3;
    const bool aon = tid < 256;
    const int acl = acb ^ ((ar >> 1) & 3);
    const ushort_t* gA = A + (size_t)(R0 + ar) * lda + acl * 8;

    const int q = lane >> 4, fr = lane & 15;

    f32x4 acc[2][NT] = {};
    for (int ks = 0; ks < ksteps; ++ks) {
        const int k0 = ks * 32;
        if (aon) async_copy16(gA + k0, &As[tid * 8]);
#pragma unroll
        for (int it = 0; it < NT / 2; ++it) {
            const int ci  = it * 512 + tid;
            const int rb  = ci >> 2, cb2 = ci & 3;
            const int clb = cb2 ^ ((rb >> 1) & 3);
            async_copy16(B + (size_t)rb * ldb + k0 + clb * 8, &Bs[ci * 8]);
        }
        __syncthreads();
        short8 a[2];
#pragma unroll
        for (int ms = 0; ms < 2; ++ms) {
            const int row = wm * 32 + ms * 16 + fr;
            a[ms] = *(const short8*)&As[(row * 4 + (q ^ ((row >> 1) & 3))) * 8];
        }
#pragma unroll
        for (int nt = 0; nt < NT; ++nt) {
            const int n = wn * (NT * 16) + nt * 16 + fr;
            const short8 b = *(const short8*)&Bs[(n * 4 + (q ^ ((n >> 1) & 3))) * 8];
#pragma unroll
            for (int ms = 0; ms < 2; ++ms)
                acc[ms][nt] = __builtin_amdgcn_mfma_f32_16x16x32_bf16(
                    a[ms], b, acc[ms][nt], 0, 0, 0);
        }
        __syncthreads();
    }

#pragma unroll
    for (int ms = 0; ms < 2; ++ms)
#pragma unroll
        for (int nt = 0; nt < NT; ++nt) {
            const int col = wn * (NT * 16) + nt * 16 + fr;
            if (col >= nlim) continue;
            const float bv = bias ? bias[col] : 0.f;
#pragma unroll
            for (int reg = 0; reg < 4; ++reg) {
                const int row = R0 + wm * 32 + ms * 16 + q * 4 + reg;
                const float v = acc[ms][nt][reg] + bv;
                if (bf16out) ((ushort_t*)Cp)[(size_t)row * ldc + col] = f2bf(v);
                else         ((float*)Cp)[(size_t)row * ldc + col] = v;
            }
        }
}

// LN(relu(Epre + enc_b)) -> Abuf cols [0,250). One wave per row, us4 loads.
__global__ __launch_bounds__(256) void k_lnenc(const ushort_t* __restrict__ Epre,
    const float* __restrict__ eb, const float* __restrict__ eg,
    const float* __restrict__ ebt, ushort_t* __restrict__ Abuf)
{
    const int wave = threadIdx.x >> 6, lane = threadIdx.x & 63;
    const int row = blockIdx.x * 4 + wave;
    const int c0 = 4 * lane;

    const us4 v = *(const us4*)&Epre[(size_t)row * 256 + c0];
    float y[4]; float sm = 0.f, sq = 0.f;
#pragma unroll
    for (int t = 0; t < 4; ++t) {
        const int cc = c0 + t;
        float z = 0.f;
        if (cc < H) z = fmaxf(bf2f(v[t]) + eb[cc], 0.f);
        y[t] = z; sm += z; sq += z * z;
    }
    sm = wave_sum_dpp(sm);
    sq = wave_sum_dpp(sq);
    const float mu = sm * (1.f / H);
    const float rs = __builtin_amdgcn_rsqf(sq * (1.f / H) - mu * mu + EPS);
    ushort_t o[4];
#pragma unroll
    for (int t = 0; t < 4; ++t) {
        const int cc = c0 + t;
        o[t] = (cc < H) ? f2bf((y[t] - mu) * rs * eg[cc] + ebt[cc]) : (ushort_t)0;
    }
    ushort_t* dst = Abuf + (size_t)row * KP + c0;
    if (c0 + 3 < H) { *(us4*)dst = (us4){o[0], o[1], o[2], o[3]}; }
    else {
        if (c0 + 1 < H) *(us2*)dst = (us2){o[0], o[1]};
    }
}

// ================= mega-fused core+cs+eff (ks-outer restructure) =================
// Block = 32 groups. Two sweeps of {4,3} jj-planes:
//   phase 1: build nj*32 A rows = LN(relu(P+Q+core_b)) in LDS (k_core math)
//   phase 2: ks outer (8 steps): stage Bs(ks) ONCE, barrier, then ALL planes
//            consume it (nj ds_read + nj*6 MFMA per barrier pair — was 6).
//   phase 3: per plane: relu/tanh + bfly16 + cross-wave gate; A4 in REGISTERS
// (registers affordable at (512,2); round-5's 1-plane loop was barrier-bound:
//  6 MFMA per vmcnt(0)-drained barrier pair, 130 barriers/block.)
__global__ __launch_bounds__(512, 2) void k_fuse(
    const ushort_t* __restrict__ PQb,
    const ushort_t* __restrict__ Wca,   // [384][256] bf16
    const float* __restrict__ core_b, const float* __restrict__ core_g,
    const float* __restrict__ core_bt,
    const float* __restrict__ ctx_b, const float* __restrict__ ctx_g,
    const float* __restrict__ ctx_bt,
    const float* __restrict__ att_b1, const float* __restrict__ att_g,
    const float* __restrict__ att_bt,
    const float* __restrict__ attW2, const float* __restrict__ att_b2,
    ushort_t* __restrict__ Abuf)
{
    __shared__ __align__(16) ushort_t As[128 * 256]; // 64 KB: up to 4 planes
    __shared__ __align__(16) ushort_t Bs[384 * 32];  // 24 KB per k-step
    __shared__ __align__(16) float red[32][36];      // [row][wn*8 + v]
    __shared__ float scal[32];                       // per-row cj (per plane)
    __shared__ float sS0[32], sS1[32];               // cross-jj row scalars
    __shared__ float swred[4][2];

    const int tid = threadIdx.x, lane = tid & 63, wave = tid >> 6;
    const int wm = wave >> 2, wn = wave & 3;
    const int q = lane >> 4, fr = lane & 15;
    const int g0 = (int)blockIdx.x * 32;

    // ---- per-lane per-col constants for the 6 nt tiles (epilogue) ----
    bool eC[6], eA[6];
    float b_[6], gw[6];
    float psgw = 0.f, psbw = 0.f;
#pragma unroll
    for (int nt = 0; nt < 6; ++nt) {
        const int col = wn * 96 + nt * 16 + fr;
        eC[nt] = col < H;
        eA[nt] = (col >= H) && (col < H + HA);
        if (eC[nt]) {
            b_[nt] = ctx_b[col]; gw[nt] = 0.f;
        } else if (eA[nt]) {
            const int ca = col - H;
            b_[nt] = att_b1[ca];
            const float ga = att_g[ca], w2 = attW2[ca];
            gw[nt] = ga * w2;
            psgw += gw[nt]; psbw += att_bt[ca] * w2;
        } else {
            b_[nt] = gw[nt] = 0.f;
        }
    }
    // row-invariant attention sums (fr-butterfly + cross-wave via LDS)
    psgw = bfly16_sum(psgw); psbw = bfly16_sum(psbw);
    if (lane == 0) { swred[wn][0] = psgw; swred[wn][1] = psbw; }  // wm dup: benign
    if (wave == 0 && lane < 32) { sS0[lane] = 0.f; sS1[lane] = 0.f; }
    __syncthreads();
    const float sgw = swred[0][0] + swred[1][0] + swred[2][0] + swred[3][0];
    const float ab2 = att_b2[0] +
        (swred[0][1] + swred[1][1] + swred[2][1] + swred[3][1]);

    // ---- phase-1 jj-invariant state: lane's 4 cols ----
    const int cL = lane * 4;
    float cb4[4], cg4[4], cbt4[4]; bool vl4[4];
#pragma unroll
    for (int t = 0; t < 4; ++t) {
        vl4[t] = (cL + t) < H;
        cb4[t] = cg4[t] = cbt4[t] = 0.f;
        if (vl4[t]) { cb4[t] = core_b[cL + t]; cg4[t] = core_g[cL + t];
                      cbt4[t] = core_bt[cL + t]; }
    }

    // GEMM A-read addressing (per-plane local row)
    const int arow = wm * 16 + fr;
    const int arsw = arow & 7;

    f32x4 A4[6] = {};   // cross-jj register accumulator (eC cols only)

    for (int sw = 0; sw < 2; ++sw) {
        const int jb = sw * 4;
        const int nj = 4 - sw;           // 4 planes, then 3

        // ---- phase 1: build nj*32 A rows, wave-per-row ----
        for (int pass = 0; pass < nj * 4; ++pass) {
            const int gr = pass * 8 + wave;     // 0..nj*32-1
            const int rl = gr & 31;             // local group row
            const int jj = jb + (gr >> 5);      // plane's jj
            const int ir = rl & 7;
            const int j  = jj + (jj >= ir ? 1 : 0);
            const us4 pu = *(const us4*)&PQb[(size_t)(g0 + rl) * PQS + cL];
            const us4 qu = *(const us4*)&PQb[
                (size_t)(g0 + (rl & ~7) + j) * PQS + 256 + cL];
            float z[4]; float sm = 0.f, sq = 0.f;
#pragma unroll
            for (int t = 0; t < 4; ++t) {
                float zz = 0.f;
                if (vl4[t]) zz = fmaxf(bf2f(pu[t]) + bf2f(qu[t]) + cb4[t], 0.f);
                z[t] = zz; sm += zz; sq = fmaf(zz, zz, sq);
            }
            sm = wave_sum_dpp(sm);
            sq = wave_sum_dpp(sq);
            const float mu = sm * (1.f / H);
            const float rs = __builtin_amdgcn_rsqf(sq * (1.f / H) - mu * mu + EPS);
            us4 o;
#pragma unroll
            for (int t = 0; t < 4; ++t)
                o[t] = vl4[t] ? f2bf((z[t] - mu) * rs * cg4[t] + cbt4[t])
                              : (ushort_t)0;
            const int p = (((lane >> 1) ^ (rl & 7)) << 1) | (lane & 1);
            *(us4*)&As[gr * 256 + p * 4] = o;
        }
        // (first ks __syncthreads drains the ds_writes — no extra barrier)

        // ---- phase 2: GEMM, ks outer, planes inner ----
        f32x4 acc[4][6] = {};
        for (int ks = 0; ks < 8; ++ks) {
#pragma unroll
            for (int it = 0; it < 3; ++it) {
                const int ci  = it * 512 + tid;
                const int rb  = ci >> 2, cb2 = ci & 3;
                const int clb = cb2 ^ ((rb >> 1) & 3);
                async_copy16(Wca + (size_t)rb * 256 + ks * 32 + clb * 8, &Bs[ci * 8]);
            }
            __syncthreads();   // Bs(ks) staged (+ As ready at ks==0)
            short8 bfr[6];
#pragma unroll
            for (int nt = 0; nt < 6; ++nt) {
                const int n = wn * 96 + nt * 16 + fr;
                bfr[nt] = *(const short8*)&Bs[(n * 4 + (q ^ ((n >> 1) & 3))) * 8];
            }
#pragma unroll
            for (int u = 0; u < 4; ++u) {
                if (u < nj) {
                    const short8 a = *(const short8*)&As[
                        (u * 32 + arow) * 256 + ((ks * 4 + q) ^ arsw) * 8];
#pragma unroll
                    for (int nt = 0; nt < 6; ++nt)
                        acc[u][nt] = __builtin_amdgcn_mfma_f32_16x16x32_bf16(
                            a, bfr[nt], acc[u][nt], 0, 0, 0);
                }
            }
            __syncthreads();   // Bs reads done before restage
        }

        // ---- phase 3: per plane transform + reductions + gate + A4 accum ----
#pragma unroll
        for (int u = 0; u < 4; ++u) {
            if (u >= nj) continue;   // wave-uniform guard
            float smc[4] = {}, sqc[4] = {}, sma[4] = {}, sqa[4] = {}, szgw[4] = {};
#pragma unroll
            for (int nt = 0; nt < 6; ++nt) {
#pragma unroll
                for (int reg = 0; reg < 4; ++reg) {
                    const float val = acc[u][nt][reg] + b_[nt];
                    if (eC[nt]) {
                        const float zz = fmaxf(val, 0.f);
                        acc[u][nt][reg] = zz;
                        smc[reg] += zz; sqc[reg] = fmaf(zz, zz, sqc[reg]);
                    } else if (eA[nt]) {
                        const float za = ftanh(val);
                        sma[reg] += za; sqa[reg] = fmaf(za, za, sqa[reg]);
                        szgw[reg] = fmaf(za, gw[nt], szgw[reg]);
                    }
                }
            }
#pragma unroll
            for (int reg = 0; reg < 4; ++reg) {
                smc[reg]  = bfly16_sum(smc[reg]);
                sqc[reg]  = bfly16_sum(sqc[reg]);
                sma[reg]  = bfly16_sum(sma[reg]);
                sqa[reg]  = bfly16_sum(sqa[reg]);
                szgw[reg] = bfly16_sum(szgw[reg]);
            }
            if (fr == 0) {
#pragma unroll
                for (int reg = 0; reg < 4; ++reg) {
                    const int row = wm * 16 + q * 4 + reg;
                    *(f32x4*)&red[row][wn * 8] =
                        (f32x4){smc[reg], sqc[reg], sma[reg], sqa[reg]};
                    red[row][wn * 8 + 4] = szgw[reg];
                }
            }
            __syncthreads();
            if (wave == 0 && lane < 32) {
                const int rr = lane;
                float s0 = 0.f, s1 = 0.f, s2 = 0.f, s3 = 0.f, s4 = 0.f;
#pragma unroll
                for (int w2 = 0; w2 < 4; ++w2) {
                    const f32x4 v = *(const f32x4*)&red[rr][w2 * 8];
                    s0 += v[0]; s1 += v[1]; s2 += v[2]; s3 += v[3];
                    s4 += red[rr][w2 * 8 + 4];
                }
                const float muC = s0 * (1.f / H);
                const float rsC = __builtin_amdgcn_rsqf(s1 * (1.f / H) - muC * muC + EPS);
                const float muA = s2 * (1.f / HA);
                const float rsA = __builtin_amdgcn_rsqf(s3 * (1.f / HA) - muA * muA + EPS);
                const float dot = rsA * (s4 - muA * sgw) + ab2;
                const float ag  = fsigmoid(dot);
                const float cj  = ag * rsC;
                scal[rr] = cj;
                sS0[rr] += ag;
                sS1[rr] = fmaf(cj, muC, sS1[rr]);
            }
            __syncthreads();
#pragma unroll
            for (int reg = 0; reg < 4; ++reg) {
                const int row = wm * 16 + q * 4 + reg;
                const float cj = scal[row];
#pragma unroll
                for (int nt = 0; nt < 6; ++nt)
                    if (eC[nt])
                        A4[nt][reg] = fmaf(cj, acc[u][nt][reg], A4[nt][reg]);
            }
        } // u
    } // sw

    // ---- final write: eff -> Abuf cols [250, 500) ----
#pragma unroll
    for (int nt = 0; nt < 6; ++nt) {
        const int col = wn * 96 + nt * 16 + fr;
        if (col >= H) continue;
        const float gc = ctx_g[col], bc = ctx_bt[col];
#pragma unroll
        for (int reg = 0; reg < 4; ++reg) {
            const int row = wm * 16 + q * 4 + reg;
            const float o = gc * (A4[nt][reg] - sS1[row]) + bc * sS0[row];
            Abuf[(size_t)(g0 + row) * KP + H + col] = f2bf(o);
        }
    }
}

extern "C" void kernel_launch(void* const* d_in, const int* in_sizes, int n_in,
                              void* d_out, int out_size, void* d_ws, size_t ws_size,
                              hipStream_t stream)
{
    const float* x      = (const float*)d_in[0];
    const float* state  = (const float*)d_in[1];
    const float* enc_W  = (const float*)d_in[2];
    const float* enc_b  = (const float*)d_in[3];
    const float* enc_g  = (const float*)d_in[4];
    const float* enc_bt = (const float*)d_in[5];
    const float* core_W = (const float*)d_in[6];
    const float* core_b = (const float*)d_in[7];
    const float* core_g = (const float*)d_in[8];
    const float* core_bt= (const float*)d_in[9];
    const float* ctx_W  = (const float*)d_in[10];
    const float* ctx_b  = (const float*)d_in[11];
    const float* ctx_g  = (const float*)d_in[12];
    const float* ctx_bt = (const float*)d_in[13];
    const float* att_W1 = (const float*)d_in[14];
    const float* att_b1 = (const float*)d_in[15];
    const float* att_g  = (const float*)d_in[16];
    const float* att_bt = (const float*)d_in[17];
    const float* att_W2 = (const float*)d_in[18];
    const float* att_b2 = (const float*)d_in[19];
    const float* out_W  = (const float*)d_in[20];
    const float* out_b  = (const float*)d_in[21];
    float* out = (float*)d_out;

    // workspace layout (ushort units) — Co/Cs eliminated by k_fuse
    ushort_t* Abuf = (ushort_t*)d_ws;                   // 16384*1088  (35.7 MB)
    ushort_t* Wt   = Abuf + (size_t)ROWS * KP;          // 256*1088
    ushort_t* Wpq  = Wt + (size_t)256 * KP;             // 512*256
    ushort_t* Wca  = Wpq + (size_t)512 * 256;           // 384*256
    ushort_t* Wenc = Wca + (size_t)384 * 256;           // 256*256
    ushort_t* Sb   = Wenc + (size_t)256 * 256;          // 16384*256   (8 MB)
    ushort_t* Epre = Sb + (size_t)ROWS * 256;           // 16384*256   (8 MB)
    ushort_t* PQb  = Epre + (size_t)ROWS * 256;         // 16384*512   (16 MB)

    k_prep  <<<2432 + ROWS, 256, 0, stream>>>(out_W, core_W, ctx_W, att_W1, enc_W,
                                              state, x, Wt, Wpq, Wca, Wenc, Sb, Abuf);
    // Epre = state @ enc_W  (bf16 MFMA, N=256 resident)
    k_gemm_nres<4><<<ROWS / 64, 512, 0, stream>>>(Sb, 256, Wenc, 256, Epre, 256,
                                                  nullptr, 8, 256, 1);
    k_lnenc <<<ROWS / 4, 256, 0, stream>>>(Epre, enc_b, enc_g, enc_bt, Abuf);
    // PQb = s1 @ [W_top | W_bot]  (bf16 MFMA, N=512 resident, bf16 out)
    k_gemm_nres<8><<<ROWS / 64, 512, 0, stream>>>(Abuf, KP, Wpq, 256, PQb, PQS,
                                                  nullptr, 8, 512, 1);
    // fused core -> cs -> eff
    k_fuse  <<<ROWS / 32, 512, 0, stream>>>(PQb, Wca,
                                            core_b, core_g, core_bt,
                                            ctx_b, ctx_g, ctx_bt,
                                            att_b1, att_g, att_bt,
                                            att_W2, att_b2, Abuf);
    // out = [s1 | eff | x] @ out_W + b  (bf16 MFMA, N=256 resident, fp32 out)
    k_gemm_nres<4><<<ROWS / 64, 512, 0, stream>>>(Abuf, KP, Wt, KP, out, H,
                                                  out_b, KP / 32, 250, 0);
}